// Round 2
// baseline (175.934 us; speedup 1.0000x reference)
//
#include <hip/hip_runtime.h>

// DFMBPSROIAlign: N ROIs x 49 parts x 10 channels, 4x4 bilinear samples/part.
// R1: (a) LDS retiled [pixel][12] so each corner read is 2x ds_read_b128 +
//     1x ds_read_b64 instead of 10x ds_read_b32 (LDS-throughput bound per R0
//     counters: 332k LDS cyc/CU == 138us measured);
//     (b) coalesced writes via (P,C,N) workspace + transpose kernel
//     (R0 WRITE_SIZE was 224MB for a 32MB output).

constexpr int C  = 10;
constexpr int PH = 7;
constexpr int PW = 7;
constexpr int H  = 34;
constexpr int W  = 34;
constexpr int P  = PH * PW;         // 49
constexpr int HW = H * W;           // 1156
constexpr int FT_C_STRIDE = P * HW; // 56644
constexpr int CP = 12;              // padded channels/pixel: 48B, 16B-aligned

#define ACC4(s, wgt, ptr4) do { float4 _v = *(ptr4); \
    (s).x += (wgt) * _v.x; (s).y += (wgt) * _v.y;    \
    (s).z += (wgt) * _v.z; (s).w += (wgt) * _v.w; } while (0)
#define ACC2(s, wgt, ptr2) do { float2 _v = *(ptr2); \
    (s).x += (wgt) * _v.x; (s).y += (wgt) * _v.y; } while (0)

template <bool COALESCED>
__global__ __launch_bounds__(256) void dfmb_phase1(
    const float* __restrict__ ft,
    const float* __restrict__ rois,
    float* __restrict__ dst,    // COALESCED ? ws (P,C,N) : out (N,C,P)
    int N)
{
    __shared__ float tile[HW * CP]; // 55488 B

    const int p  = blockIdx.y;
    const int ph = p / PW;
    const int pw = p - ph * PW;

    // Stage this part's slab: tile[pixel*12 + c]
    const float* __restrict__ src = ft + p * HW;
    for (int i = threadIdx.x; i < C * HW; i += 256) {
        int c = i / HW;
        int r = i - c * HW;
        tile[r * CP + c] = src[c * FT_C_STRIDE + r];
    }
    __syncthreads();

    const int n = blockIdx.x * 256 + threadIdx.x;
    if (n >= N) return;

    float4 s0 = {0.f, 0.f, 0.f, 0.f};
    float4 s1 = {0.f, 0.f, 0.f, 0.f};
    float2 s2 = {0.f, 0.f};
    float count = 0.0f;

    // Coordinate setup — contraction OFF so floor() args match the un-fused
    // reference rounding (verified passing in R0/R1).
    float wstart, hstart, sub_w, sub_h;
    {
#pragma clang fp contract(off)
        const float inv_stride = 0.0625f;
        float rsw = rois[n * 5 + 1] * inv_stride;
        float rsh = rois[n * 5 + 2] * inv_stride;
        float rew = rois[n * 5 + 3] * inv_stride;
        float reh = rois[n * 5 + 4] * inv_stride;
        float roi_h = reh - rsh; if (!(roi_h > 0.1f)) roi_h = 0.1f;
        float roi_w = rew - rsw; if (!(roi_w > 0.1f)) roi_w = 0.1f;
        float bin_h = roi_h / 7.0f;
        float bin_w = roi_w / 7.0f;
        sub_h = bin_h * 0.25f;
        sub_w = bin_w * 0.25f;
        hstart = floorf(rsh + (float)ph * bin_h);
        wstart = floorf(rsw + (float)pw * bin_w);
    }

#pragma unroll
    for (int ih = 0; ih < 4; ++ih) {
#pragma unroll
        for (int iw = 0; iw < 4; ++iw) {
            float w, h;
            {
#pragma clang fp contract(off)
                w = wstart + ((float)iw + 0.5f) * sub_w;
                h = hstart + ((float)ih + 0.5f) * sub_h;
            }
            if (!(w > -1.0f && w < 34.0f && h > -1.0f && h < 34.0f)) continue;
            count += 1.0f;

            float x1f = floorf(w), x2f = ceilf(w);
            float y1f = floorf(h), y2f = ceilf(h);
            float x1v = (x1f >= 0.0f && x1f < 34.0f) ? 1.0f : 0.0f;
            float x2v = (x2f >= 0.0f && x2f < 34.0f) ? 1.0f : 0.0f;
            float y1v = (y1f >= 0.0f && y1f < 34.0f) ? 1.0f : 0.0f;
            float y2v = (y2f >= 0.0f && y2f < 34.0f) ? 1.0f : 0.0f;
            int x1 = (int)fminf(fmaxf(x1f, 0.0f), 33.0f);
            int x2 = (int)fminf(fmaxf(x2f, 0.0f), 33.0f);
            int y1 = (int)fminf(fmaxf(y1f, 0.0f), 33.0f);
            int y2 = (int)fminf(fmaxf(y2f, 0.0f), 33.0f);
            float dx = w - (float)x1;
            float dy = h - (float)y1;

            float w11 = (1.0f - dx) * (1.0f - dy) * (x1v * y1v);
            float w12 = (1.0f - dx) * dy          * (x1v * y2v);
            float w21 = dx          * (1.0f - dy) * (x2v * y1v);
            float w22 = dx          * dy          * (x2v * y2v);

            const float* t11 = &tile[(y1 * W + x1) * CP];
            const float* t12 = &tile[(y2 * W + x1) * CP];
            const float* t21 = &tile[(y1 * W + x2) * CP];
            const float* t22 = &tile[(y2 * W + x2) * CP];

            ACC4(s0, w11, (const float4*)(t11));
            ACC4(s1, w11, (const float4*)(t11 + 4));
            ACC2(s2, w11, (const float2*)(t11 + 8));
            ACC4(s0, w12, (const float4*)(t12));
            ACC4(s1, w12, (const float4*)(t12 + 4));
            ACC2(s2, w12, (const float2*)(t12 + 8));
            ACC4(s0, w21, (const float4*)(t21));
            ACC4(s1, w21, (const float4*)(t21 + 4));
            ACC2(s2, w21, (const float2*)(t21 + 8));
            ACC4(s0, w22, (const float4*)(t22));
            ACC4(s1, w22, (const float4*)(t22 + 4));
            ACC2(s2, w22, (const float2*)(t22 + 8));
        }
    }

    float cnt = count > 0.0f ? count : 1.0f;
    float inv = 1.0f / cnt;
    float r[10] = { s0.x * inv, s0.y * inv, s0.z * inv, s0.w * inv,
                    s1.x * inv, s1.y * inv, s1.z * inv, s1.w * inv,
                    s2.x * inv, s2.y * inv };

    if (COALESCED) {
        // ws[(p*C + c)*N + n] — lane-consecutive n => fully coalesced
        float* __restrict__ o = dst + (size_t)(p * C) * N + n;
#pragma unroll
        for (int c = 0; c < C; ++c) o[(size_t)c * N] = r[c];
    } else {
        float* __restrict__ o = dst + (size_t)n * (C * P) + p;
#pragma unroll
        for (int c = 0; c < C; ++c) o[c * P] = r[c];
    }
}

// Transpose (P,C,N) -> (N,C,P). One block per n: writes coalesced,
// scattered reads stay in L2 (ws rows reused across consecutive n-blocks).
__global__ __launch_bounds__(256) void dfmb_phase2(
    const float* __restrict__ ws, float* __restrict__ out, int N)
{
    const int n = blockIdx.x;
    float* __restrict__ o = out + (size_t)n * (C * P);
    for (int r = threadIdx.x; r < C * P; r += 256) {
        int c = r / P;          // r = c*49 + p
        int pp = r - c * P;
        o[r] = ws[(size_t)(pp * C + c) * N + n];
    }
}

extern "C" void kernel_launch(void* const* d_in, const int* in_sizes, int n_in,
                              void* d_out, int out_size, void* d_ws, size_t ws_size,
                              hipStream_t stream) {
    const float* ft   = (const float*)d_in[0];
    const float* rois = (const float*)d_in[1];
    float* out = (float*)d_out;
    const int N = in_sizes[1] / 5;

    dim3 grid((N + 255) / 256, P);
    const size_t need = (size_t)P * C * N * sizeof(float);
    if (d_ws != nullptr && ws_size >= need) {
        float* ws = (float*)d_ws;
        dfmb_phase1<true><<<grid, dim3(256), 0, stream>>>(ft, rois, ws, N);
        dfmb_phase2<<<dim3(N), dim3(256), 0, stream>>>(ws, out, N);
    } else {
        dfmb_phase1<false><<<grid, dim3(256), 0, stream>>>(ft, rois, out, N);
    }
}

// Round 3
// 135.468 us; speedup vs baseline: 1.2987x; 1.2987x over previous
//
#include <hip/hip_runtime.h>

// DFMBPSROIAlign. R2:
//  phase1: separable-footprint rewrite — the 16 bilinear samples factor into
//    outer product Wx(<=4 cols) x Wy(<=4 rows); <=16 LDS pixel reads instead
//    of 64 corner reads (R1 was LDS-instruction bound at ~80us).
//  phase2: R1's scattered-read transpose thrashed per-XCD L2 (~90us!).
//    ws now stored as ws[out_col][n]; 64x64 LDS-tiled transpose, coalesced
//    256B on both sides.

constexpr int C  = 10;
constexpr int PH = 7;
constexpr int PW = 7;
constexpr int H  = 34;
constexpr int W  = 34;
constexpr int P  = PH * PW;         // 49
constexpr int HW = H * W;           // 1156
constexpr int FT_C_STRIDE = P * HW; // 56644
constexpr int CP = 12;              // padded channels/pixel (48B, 16B-aligned)
constexpr int R  = C * P;           // 490 output cols per n

template <bool COALESCED>
__global__ __launch_bounds__(256) void dfmb_phase1(
    const float* __restrict__ ft,
    const float* __restrict__ rois,
    float* __restrict__ dst,    // COALESCED ? ws[(c*P+p)*N + n] : out (N,C,P)
    int N)
{
    __shared__ float tile[HW * CP]; // 55488 B

    const int p  = blockIdx.y;
    const int ph = p / PW;
    const int pw = p - ph * PW;

    // Stage slab as tile[pixel*12 + c]; float4 global reads (1156 = 4*289).
    const float* __restrict__ src = ft + p * HW;
    for (int i = threadIdx.x; i < C * (HW / 4); i += 256) {
        int c = i / (HW / 4);
        int q = i - c * (HW / 4);
        float4 v = ((const float4*)(src + c * FT_C_STRIDE))[q];
        float* t = &tile[(4 * q) * CP + c];
        t[0] = v.x; t[CP] = v.y; t[2 * CP] = v.z; t[3 * CP] = v.w;
    }
    __syncthreads();

    const int n = blockIdx.x * 256 + threadIdx.x;
    if (n >= N) return;

    // Coordinate setup — contraction OFF so floor() args match the reference
    // rounding (floor flips are the real accuracy hazard; verified R0/R1).
    float wstart, hstart, sub_w, sub_h;
    {
#pragma clang fp contract(off)
        const float inv_stride = 0.0625f;
        float rsw = rois[n * 5 + 1] * inv_stride;
        float rsh = rois[n * 5 + 2] * inv_stride;
        float rew = rois[n * 5 + 3] * inv_stride;
        float reh = rois[n * 5 + 4] * inv_stride;
        float roi_h = reh - rsh; if (!(roi_h > 0.1f)) roi_h = 0.1f;
        float roi_w = rew - rsw; if (!(roi_w > 0.1f)) roi_w = 0.1f;
        float bin_h = roi_h / 7.0f;
        float bin_w = roi_w / 7.0f;
        sub_h = bin_h * 0.25f;
        sub_w = bin_w * 0.25f;
        hstart = floorf(rsh + (float)ph * bin_h);
        wstart = floorf(rsw + (float)pw * bin_w);
    }

    // ---- separable 1-D weight footprints ----
    float Xw0 = 0.f, Xw1 = 0.f, Xw2 = 0.f, Xw3 = 0.f, cntx = 0.f;
    int xbase = 0;
#pragma unroll
    for (int iw = 0; iw < 4; ++iw) {
        float w;
        {
#pragma clang fp contract(off)
            w = wstart + ((float)iw + 0.5f) * sub_w;
        }
        float kw  = (w > -1.0f && w < 34.0f) ? 1.0f : 0.0f;
        float x1f = floorf(w), x2f = ceilf(w);
        float x1v = (x1f >= 0.0f && x1f < 34.0f) ? 1.0f : 0.0f;
        float x2v = (x2f >= 0.0f && x2f < 34.0f) ? 1.0f : 0.0f;
        int x1 = (int)fminf(fmaxf(x1f, 0.0f), 33.0f);
        int x2 = (int)fminf(fmaxf(x2f, 0.0f), 33.0f);
        float dx = w - (float)x1;           // vs CLAMPED corner (ref semantics)
        if (iw == 0) xbase = x1;            // minimal column (w monotone in iw)
        float a = kw * (1.0f - dx) * x1v;
        float b = kw * dx * x2v;
        int i1 = x1 - xbase, i2 = x2 - xbase;   // in [0,3]
        Xw0 += (i1 == 0) ? a : 0.f;  Xw1 += (i1 == 1) ? a : 0.f;
        Xw2 += (i1 == 2) ? a : 0.f;  Xw3 += (i1 == 3) ? a : 0.f;
        Xw0 += (i2 == 0) ? b : 0.f;  Xw1 += (i2 == 1) ? b : 0.f;
        Xw2 += (i2 == 2) ? b : 0.f;  Xw3 += (i2 == 3) ? b : 0.f;
        cntx += kw;
    }

    float Yw0 = 0.f, Yw1 = 0.f, Yw2 = 0.f, Yw3 = 0.f, cnty = 0.f;
    int ybase = 0;
#pragma unroll
    for (int ih = 0; ih < 4; ++ih) {
        float h;
        {
#pragma clang fp contract(off)
            h = hstart + ((float)ih + 0.5f) * sub_h;
        }
        float kh  = (h > -1.0f && h < 34.0f) ? 1.0f : 0.0f;
        float y1f = floorf(h), y2f = ceilf(h);
        float y1v = (y1f >= 0.0f && y1f < 34.0f) ? 1.0f : 0.0f;
        float y2v = (y2f >= 0.0f && y2f < 34.0f) ? 1.0f : 0.0f;
        int y1 = (int)fminf(fmaxf(y1f, 0.0f), 33.0f);
        int y2 = (int)fminf(fmaxf(y2f, 0.0f), 33.0f);
        float dy = h - (float)y1;
        if (ih == 0) ybase = y1;
        float a = kh * (1.0f - dy) * y1v;
        float b = kh * dy * y2v;
        int i1 = y1 - ybase, i2 = y2 - ybase;
        Yw0 += (i1 == 0) ? a : 0.f;  Yw1 += (i1 == 1) ? a : 0.f;
        Yw2 += (i1 == 2) ? a : 0.f;  Yw3 += (i1 == 3) ? a : 0.f;
        Yw0 += (i2 == 0) ? b : 0.f;  Yw1 += (i2 == 1) ? b : 0.f;
        Yw2 += (i2 == 2) ? b : 0.f;  Yw3 += (i2 == 3) ? b : 0.f;
        cnty += kh;
    }

    // ---- accumulate over (<=4 x <=4) pixel footprint ----
    float4 s0 = {0.f, 0.f, 0.f, 0.f};
    float4 s1 = {0.f, 0.f, 0.f, 0.f};
    float2 s2 = {0.f, 0.f};
#pragma unroll
    for (int cy = 0; cy < 4; ++cy) {
        float wy = (cy == 0) ? Yw0 : (cy == 1) ? Yw1 : (cy == 2) ? Yw2 : Yw3;
        if (wy != 0.0f) {
            int yy = min(ybase + cy, 33);   // weight==0 beyond real footprint
            const float* rowp = &tile[yy * (W * CP)];
#pragma unroll
            for (int cx = 0; cx < 4; ++cx) {
                float wx = (cx == 0) ? Xw0 : (cx == 1) ? Xw1
                         : (cx == 2) ? Xw2 : Xw3;
                float wgt = wy * wx;
                if (wgt != 0.0f) {
                    int xx = min(xbase + cx, 33);
                    const float* t = rowp + xx * CP;
                    float4 v0 = *(const float4*)(t);
                    float4 v1 = *(const float4*)(t + 4);
                    float2 v2 = *(const float2*)(t + 8);
                    s0.x += wgt * v0.x; s0.y += wgt * v0.y;
                    s0.z += wgt * v0.z; s0.w += wgt * v0.w;
                    s1.x += wgt * v1.x; s1.y += wgt * v1.y;
                    s1.z += wgt * v1.z; s1.w += wgt * v1.w;
                    s2.x += wgt * v2.x; s2.y += wgt * v2.y;
                }
            }
        }
    }

    float cnt = cntx * cnty;                // exact small ints
    if (!(cnt > 0.0f)) cnt = 1.0f;
    float inv = 1.0f / cnt;
    float r[10] = { s0.x * inv, s0.y * inv, s0.z * inv, s0.w * inv,
                    s1.x * inv, s1.y * inv, s1.z * inv, s1.w * inv,
                    s2.x * inv, s2.y * inv };

    if (COALESCED) {
        // ws[(c*P + p)*N + n]: ws row index == output column index c*P+p
        float* __restrict__ o = dst + (size_t)p * N + n;
#pragma unroll
        for (int c = 0; c < C; ++c) o[(size_t)c * (P * N)] = r[c];
    } else {
        float* __restrict__ o = dst + (size_t)n * R + p;
#pragma unroll
        for (int c = 0; c < C; ++c) o[c * P] = r[c];
    }
}

// 64x64 LDS-tiled transpose: ws (R=490, N) -> out (N, R). Both sides
// coalesced (256B per 64-lane group).
__global__ __launch_bounds__(256) void dfmb_phase2(
    const float* __restrict__ ws, float* __restrict__ out, int N)
{
    __shared__ float t[64][65];
    const int n0 = blockIdx.x * 64;
    const int r0 = blockIdx.y * 64;
    const int ln = threadIdx.x & 63;
    const int sb = threadIdx.x >> 6;   // 0..3

#pragma unroll
    for (int i = 0; i < 16; ++i) {
        int rr = i * 4 + sb;
        int r  = r0 + rr;
        if (r < R) t[rr][ln] = ws[(size_t)r * N + n0 + ln];
    }
    __syncthreads();
#pragma unroll
    for (int i = 0; i < 16; ++i) {
        int n = n0 + i * 4 + sb;
        int r = r0 + ln;
        if (r < R) out[(size_t)n * R + r] = t[ln][i * 4 + sb];
    }
}

extern "C" void kernel_launch(void* const* d_in, const int* in_sizes, int n_in,
                              void* d_out, int out_size, void* d_ws, size_t ws_size,
                              hipStream_t stream) {
    const float* ft   = (const float*)d_in[0];
    const float* rois = (const float*)d_in[1];
    float* out = (float*)d_out;
    const int N = in_sizes[1] / 5;

    dim3 grid1((N + 255) / 256, P);
    const size_t need = (size_t)R * N * sizeof(float);
    if (d_ws != nullptr && ws_size >= need && (N % 64) == 0) {
        float* ws = (float*)d_ws;
        dfmb_phase1<true><<<grid1, dim3(256), 0, stream>>>(ft, rois, ws, N);
        dim3 grid2(N / 64, (R + 63) / 64);
        dfmb_phase2<<<grid2, dim3(256), 0, stream>>>(ws, out, N);
    } else {
        dfmb_phase1<false><<<grid1, dim3(256), 0, stream>>>(ft, rois, out, N);
    }
}

// Round 4
// 110.381 us; speedup vs baseline: 1.5939x; 1.2273x over previous
//
#include <hip/hip_runtime.h>

// DFMBPSROIAlign. R3:
//  phase1: blockDim 512 (16 waves/CU vs 8), staging writes restructured from
//    32-way to 8-way bank conflicts (R2's SQ_LDS_BANK_CONFLICT was flat at
//    2.3e7 because staging, not footprint reads, owned the conflicts).
//  ws layout now blocked [n/64][r][n%64] so phase2 is a per-block contiguous
//    125KB->125KB transpose (R2 phase2 read 64KB-strided rows across XCDs:
//    ~60us for a 64MB job). Classic 65-pad LDS tile, conflict-free.

constexpr int C  = 10;
constexpr int PH = 7;
constexpr int PW = 7;
constexpr int H  = 34;
constexpr int W  = 34;
constexpr int P  = PH * PW;         // 49
constexpr int HW = H * W;           // 1156
constexpr int FT_C_STRIDE = P * HW; // 56644
constexpr int CP = 12;              // padded channels/pixel (48B, 16B-aligned)
constexpr int R  = C * P;           // 490 output cols per n

template <bool COALESCED>
__global__ __launch_bounds__(512, 4) void dfmb_phase1(
    const float* __restrict__ ft,
    const float* __restrict__ rois,
    float* __restrict__ dst,    // COALESCED ? ws[n/64][c*P+p][n%64] : out (N,C,P)
    int N)
{
    __shared__ float tile[HW * CP]; // 55488 B

    const int p  = blockIdx.y;
    const int ph = p / PW;
    const int pw = p - ph * PW;

    // Stage slab as tile[pixel*12 + c]. Scalar path: lane-consecutive r ->
    // coalesced 256B global reads; LDS bank stride 12 -> 8-way (was 32-way).
    const float* __restrict__ src = ft + p * HW;
    for (int i = threadIdx.x; i < C * HW; i += 512) {
        int c = i / HW;
        int r = i - c * HW;
        tile[r * CP + c] = src[c * FT_C_STRIDE + r];
    }
    __syncthreads();

    const int n = blockIdx.x * 512 + threadIdx.x;
    if (n >= N) return;

    // Coordinate setup — contraction OFF so floor() args match the reference
    // rounding (verified passing R0-R2).
    float wstart, hstart, sub_w, sub_h;
    {
#pragma clang fp contract(off)
        const float inv_stride = 0.0625f;
        float rsw = rois[n * 5 + 1] * inv_stride;
        float rsh = rois[n * 5 + 2] * inv_stride;
        float rew = rois[n * 5 + 3] * inv_stride;
        float reh = rois[n * 5 + 4] * inv_stride;
        float roi_h = reh - rsh; if (!(roi_h > 0.1f)) roi_h = 0.1f;
        float roi_w = rew - rsw; if (!(roi_w > 0.1f)) roi_w = 0.1f;
        float bin_h = roi_h / 7.0f;
        float bin_w = roi_w / 7.0f;
        sub_h = bin_h * 0.25f;
        sub_w = bin_w * 0.25f;
        hstart = floorf(rsh + (float)ph * bin_h);
        wstart = floorf(rsw + (float)pw * bin_w);
    }

    // ---- separable 1-D weight footprints (<=4 cols x <=4 rows) ----
    float Xw0 = 0.f, Xw1 = 0.f, Xw2 = 0.f, Xw3 = 0.f, cntx = 0.f;
    int xbase = 0;
#pragma unroll
    for (int iw = 0; iw < 4; ++iw) {
        float w;
        {
#pragma clang fp contract(off)
            w = wstart + ((float)iw + 0.5f) * sub_w;
        }
        float kw  = (w > -1.0f && w < 34.0f) ? 1.0f : 0.0f;
        float x1f = floorf(w), x2f = ceilf(w);
        float x1v = (x1f >= 0.0f && x1f < 34.0f) ? 1.0f : 0.0f;
        float x2v = (x2f >= 0.0f && x2f < 34.0f) ? 1.0f : 0.0f;
        int x1 = (int)fminf(fmaxf(x1f, 0.0f), 33.0f);
        int x2 = (int)fminf(fmaxf(x2f, 0.0f), 33.0f);
        float dx = w - (float)x1;           // vs CLAMPED corner (ref semantics)
        if (iw == 0) xbase = x1;            // minimal column (w monotone in iw)
        float a = kw * (1.0f - dx) * x1v;
        float b = kw * dx * x2v;
        int i1 = x1 - xbase, i2 = x2 - xbase;
        Xw0 += (i1 == 0) ? a : 0.f;  Xw1 += (i1 == 1) ? a : 0.f;
        Xw2 += (i1 == 2) ? a : 0.f;  Xw3 += (i1 == 3) ? a : 0.f;
        Xw0 += (i2 == 0) ? b : 0.f;  Xw1 += (i2 == 1) ? b : 0.f;
        Xw2 += (i2 == 2) ? b : 0.f;  Xw3 += (i2 == 3) ? b : 0.f;
        cntx += kw;
    }

    float Yw0 = 0.f, Yw1 = 0.f, Yw2 = 0.f, Yw3 = 0.f, cnty = 0.f;
    int ybase = 0;
#pragma unroll
    for (int ih = 0; ih < 4; ++ih) {
        float h;
        {
#pragma clang fp contract(off)
            h = hstart + ((float)ih + 0.5f) * sub_h;
        }
        float kh  = (h > -1.0f && h < 34.0f) ? 1.0f : 0.0f;
        float y1f = floorf(h), y2f = ceilf(h);
        float y1v = (y1f >= 0.0f && y1f < 34.0f) ? 1.0f : 0.0f;
        float y2v = (y2f >= 0.0f && y2f < 34.0f) ? 1.0f : 0.0f;
        int y1 = (int)fminf(fmaxf(y1f, 0.0f), 33.0f);
        int y2 = (int)fminf(fmaxf(y2f, 0.0f), 33.0f);
        float dy = h - (float)y1;
        if (ih == 0) ybase = y1;
        float a = kh * (1.0f - dy) * y1v;
        float b = kh * dy * y2v;
        int i1 = y1 - ybase, i2 = y2 - ybase;
        Yw0 += (i1 == 0) ? a : 0.f;  Yw1 += (i1 == 1) ? a : 0.f;
        Yw2 += (i1 == 2) ? a : 0.f;  Yw3 += (i1 == 3) ? a : 0.f;
        Yw0 += (i2 == 0) ? b : 0.f;  Yw1 += (i2 == 1) ? b : 0.f;
        Yw2 += (i2 == 2) ? b : 0.f;  Yw3 += (i2 == 3) ? b : 0.f;
        cnty += kh;
    }

    // ---- accumulate over (<=4 x <=4) pixel footprint ----
    float4 s0 = {0.f, 0.f, 0.f, 0.f};
    float4 s1 = {0.f, 0.f, 0.f, 0.f};
    float2 s2 = {0.f, 0.f};
#pragma unroll
    for (int cy = 0; cy < 4; ++cy) {
        float wy = (cy == 0) ? Yw0 : (cy == 1) ? Yw1 : (cy == 2) ? Yw2 : Yw3;
        if (wy != 0.0f) {
            int yy = min(ybase + cy, 33);
            const float* rowp = &tile[yy * (W * CP)];
#pragma unroll
            for (int cx = 0; cx < 4; ++cx) {
                float wx = (cx == 0) ? Xw0 : (cx == 1) ? Xw1
                         : (cx == 2) ? Xw2 : Xw3;
                float wgt = wy * wx;
                if (wgt != 0.0f) {
                    int xx = min(xbase + cx, 33);
                    const float* t = rowp + xx * CP;
                    float4 v0 = *(const float4*)(t);
                    float4 v1 = *(const float4*)(t + 4);
                    float2 v2 = *(const float2*)(t + 8);
                    s0.x += wgt * v0.x; s0.y += wgt * v0.y;
                    s0.z += wgt * v0.z; s0.w += wgt * v0.w;
                    s1.x += wgt * v1.x; s1.y += wgt * v1.y;
                    s1.z += wgt * v1.z; s1.w += wgt * v1.w;
                    s2.x += wgt * v2.x; s2.y += wgt * v2.y;
                }
            }
        }
    }

    float cnt = cntx * cnty;
    if (!(cnt > 0.0f)) cnt = 1.0f;
    float inv = 1.0f / cnt;
    float r[10] = { s0.x * inv, s0.y * inv, s0.z * inv, s0.w * inv,
                    s1.x * inv, s1.y * inv, s1.z * inv, s1.w * inv,
                    s2.x * inv, s2.y * inv };

    if (COALESCED) {
        // ws[(n>>6)*R*64 + (c*P+p)*64 + (n&63)] — coalesced 256B runs
        float* __restrict__ o = dst + (size_t)(n >> 6) * (R * 64)
                                    + (size_t)p * 64 + (n & 63);
#pragma unroll
        for (int c = 0; c < C; ++c) o[(size_t)(c * P) * 64] = r[c];
    } else {
        float* __restrict__ o = dst + (size_t)n * R + p;
#pragma unroll
        for (int c = 0; c < C; ++c) o[c * P] = r[c];
    }
}

// Per-block contiguous transpose: ws[nblk][r][nl] (64 n x 245 r half-slab,
// 62.7KB) -> out[n][r]. 65-pad LDS tile: conflict-free banks both phases,
// coalesced global both phases.
constexpr int TR = 245;             // r-tile (490/2)
__global__ __launch_bounds__(1024) void dfmb_phase2(
    const float* __restrict__ ws, float* __restrict__ out, int N)
{
    __shared__ float t[TR * 65];    // 63700 B
    const int nblk = blockIdx.x;
    const int r0   = blockIdx.y * TR;
    const float* __restrict__ srcb = ws + (size_t)nblk * (R * 64) + (size_t)r0 * 64;

    // Load 245 rows x 64 nl (contiguous 62.7KB) via float4.
    for (int i = threadIdx.x; i < TR * 16; i += 1024) {
        int rr  = i >> 4;            // row
        int nl4 = (i & 15) * 4;
        float4 v = ((const float4*)srcb)[i];
        float* tp = &t[rr * 65 + nl4];
        tp[0] = v.x; tp[1] = v.y; tp[2] = v.z; tp[3] = v.w;
    }
    __syncthreads();

    // Write out[n0+nl][r0..r0+244]: lane-consecutive r -> coalesced.
    const int n0 = nblk * 64;
    for (int i = threadIdx.x; i < 64 * TR; i += 1024) {
        int nl = i / TR;
        int r  = i - nl * TR;
        out[(size_t)(n0 + nl) * R + r0 + r] = t[r * 65 + nl];
    }
}

extern "C" void kernel_launch(void* const* d_in, const int* in_sizes, int n_in,
                              void* d_out, int out_size, void* d_ws, size_t ws_size,
                              hipStream_t stream) {
    const float* ft   = (const float*)d_in[0];
    const float* rois = (const float*)d_in[1];
    float* out = (float*)d_out;
    const int N = in_sizes[1] / 5;

    dim3 grid1((N + 511) / 512, P);
    const size_t need = (size_t)R * N * sizeof(float);
    if (d_ws != nullptr && ws_size >= need && (N % 64) == 0) {
        float* ws = (float*)d_ws;
        dfmb_phase1<true><<<grid1, dim3(512), 0, stream>>>(ft, rois, ws, N);
        dim3 grid2(N / 64, 2);
        dfmb_phase2<<<grid2, dim3(1024), 0, stream>>>(ws, out, N);
    } else {
        dfmb_phase1<false><<<grid1, dim3(512), 0, stream>>>(ft, rois, out, N);
    }
}

// Round 5
// 103.703 us; speedup vs baseline: 1.6965x; 1.0644x over previous
//
#include <hip/hip_runtime.h>

// DFMBPSROIAlign. R5: fused single-pass kernel.
//  - ft (2.27MB) fits per-XCD L2 entirely; read bilinear-footprint pixels
//    straight from a pre-swizzled ftT[p][pixel][c pad12] (global, L2-hot)
//    instead of LDS slabs (R4: 2.3e7 LDS bank-conflict cycles from random
//    48B-stride ds_read_b128 gathers ~= 37us/CU).
//  - block = 16 n x all 49 p; results staged in LDS [n][c*49+p] (stride-10
//    banks, conflict-free) then one contiguous coalesced float4 writeout.
//    Eliminates phase2 transpose (-64MB HBM traffic).

constexpr int C  = 10;
constexpr int PH = 7;
constexpr int PW = 7;
constexpr int H  = 34;
constexpr int W  = 34;
constexpr int P  = PH * PW;         // 49
constexpr int HW = H * W;           // 1156
constexpr int FT_C_STRIDE = P * HW; // 56644
constexpr int CP = 12;              // padded channels/pixel (48B, 16B-aligned)
constexpr int R  = C * P;           // 490
constexpr int NB = 16;              // n per block (fused kernel)

// ---- Kernel A: swizzle ft (C,P,H,W) -> ftT[p][pix][c] (c padded to 12) ----
__global__ __launch_bounds__(256) void dfmb_swizzle(
    const float* __restrict__ ft, float* __restrict__ ftT)
{
    const int p = blockIdx.x;
    const int c = blockIdx.y;
    const float* __restrict__ src = ft + (size_t)c * FT_C_STRIDE + p * HW;
    float* __restrict__ dst = ftT + (size_t)p * (HW * CP) + c;
    for (int pix = threadIdx.x; pix < HW; pix += 256)
        dst[(size_t)pix * CP] = src[pix];
}

// ---- fused main kernel ----
__global__ __launch_bounds__(256, 4) void dfmb_fused(
    const float* __restrict__ ftT,
    const float* __restrict__ rois,
    float* __restrict__ out,
    int N)
{
    __shared__ float olds[NB * R];  // 31360 B, [n_loc][c*49+p]

    const int n0 = blockIdx.x * NB;

    // 784 (p, n_loc) pairs over 256 threads: 4 passes.
    for (int k = 0; k < 4; ++k) {
        const int j = threadIdx.x + k * 256;
        if (j < P * NB) {
            const int p     = j >> 4;      // j / 16
            const int n_loc = j & 15;
            const int n     = n0 + n_loc;
            const int ph = p / PW;
            const int pw = p - ph * PW;

            // Coordinate setup — contraction OFF so floor() args match the
            // reference rounding (verified passing R0-R4).
            float wstart, hstart, sub_w, sub_h;
            {
#pragma clang fp contract(off)
                const float inv_stride = 0.0625f;
                float rsw = rois[n * 5 + 1] * inv_stride;
                float rsh = rois[n * 5 + 2] * inv_stride;
                float rew = rois[n * 5 + 3] * inv_stride;
                float reh = rois[n * 5 + 4] * inv_stride;
                float roi_h = reh - rsh; if (!(roi_h > 0.1f)) roi_h = 0.1f;
                float roi_w = rew - rsw; if (!(roi_w > 0.1f)) roi_w = 0.1f;
                float bin_h = roi_h / 7.0f;
                float bin_w = roi_w / 7.0f;
                sub_h = bin_h * 0.25f;
                sub_w = bin_w * 0.25f;
                hstart = floorf(rsh + (float)ph * bin_h);
                wstart = floorf(rsw + (float)pw * bin_w);
            }

            // ---- separable 1-D weight footprints (<=4 cols x <=4 rows) ----
            float Xw0 = 0.f, Xw1 = 0.f, Xw2 = 0.f, Xw3 = 0.f, cntx = 0.f;
            int xbase = 0;
#pragma unroll
            for (int iw = 0; iw < 4; ++iw) {
                float w;
                {
#pragma clang fp contract(off)
                    w = wstart + ((float)iw + 0.5f) * sub_w;
                }
                float kw  = (w > -1.0f && w < 34.0f) ? 1.0f : 0.0f;
                float x1f = floorf(w), x2f = ceilf(w);
                float x1v = (x1f >= 0.0f && x1f < 34.0f) ? 1.0f : 0.0f;
                float x2v = (x2f >= 0.0f && x2f < 34.0f) ? 1.0f : 0.0f;
                int x1 = (int)fminf(fmaxf(x1f, 0.0f), 33.0f);
                int x2 = (int)fminf(fmaxf(x2f, 0.0f), 33.0f);
                float dx = w - (float)x1;   // vs CLAMPED corner (ref semantics)
                if (iw == 0) xbase = x1;    // minimal column (w monotone in iw)
                float a = kw * (1.0f - dx) * x1v;
                float b = kw * dx * x2v;
                int i1 = x1 - xbase, i2 = x2 - xbase;
                Xw0 += (i1 == 0) ? a : 0.f;  Xw1 += (i1 == 1) ? a : 0.f;
                Xw2 += (i1 == 2) ? a : 0.f;  Xw3 += (i1 == 3) ? a : 0.f;
                Xw0 += (i2 == 0) ? b : 0.f;  Xw1 += (i2 == 1) ? b : 0.f;
                Xw2 += (i2 == 2) ? b : 0.f;  Xw3 += (i2 == 3) ? b : 0.f;
                cntx += kw;
            }

            float Yw0 = 0.f, Yw1 = 0.f, Yw2 = 0.f, Yw3 = 0.f, cnty = 0.f;
            int ybase = 0;
#pragma unroll
            for (int ih = 0; ih < 4; ++ih) {
                float h;
                {
#pragma clang fp contract(off)
                    h = hstart + ((float)ih + 0.5f) * sub_h;
                }
                float kh  = (h > -1.0f && h < 34.0f) ? 1.0f : 0.0f;
                float y1f = floorf(h), y2f = ceilf(h);
                float y1v = (y1f >= 0.0f && y1f < 34.0f) ? 1.0f : 0.0f;
                float y2v = (y2f >= 0.0f && y2f < 34.0f) ? 1.0f : 0.0f;
                int y1 = (int)fminf(fmaxf(y1f, 0.0f), 33.0f);
                int y2 = (int)fminf(fmaxf(y2f, 0.0f), 33.0f);
                float dy = h - (float)y1;
                if (ih == 0) ybase = y1;
                float a = kh * (1.0f - dy) * y1v;
                float b = kh * dy * y2v;
                int i1 = y1 - ybase, i2 = y2 - ybase;
                Yw0 += (i1 == 0) ? a : 0.f;  Yw1 += (i1 == 1) ? a : 0.f;
                Yw2 += (i1 == 2) ? a : 0.f;  Yw3 += (i1 == 3) ? a : 0.f;
                Yw0 += (i2 == 0) ? b : 0.f;  Yw1 += (i2 == 1) ? b : 0.f;
                Yw2 += (i2 == 2) ? b : 0.f;  Yw3 += (i2 == 3) ? b : 0.f;
                cnty += kh;
            }

            // ---- accumulate over (<=4 x <=4) footprint, global L2-hot reads ----
            const float* __restrict__ slab = ftT + (size_t)p * (HW * CP);
            float4 s0 = {0.f, 0.f, 0.f, 0.f};
            float4 s1 = {0.f, 0.f, 0.f, 0.f};
            float2 s2 = {0.f, 0.f};
#pragma unroll
            for (int cy = 0; cy < 4; ++cy) {
                float wy = (cy == 0) ? Yw0 : (cy == 1) ? Yw1 : (cy == 2) ? Yw2 : Yw3;
                if (wy != 0.0f) {
                    int yy = min(ybase + cy, 33);
                    const float* rowp = slab + yy * (W * CP);
#pragma unroll
                    for (int cx = 0; cx < 4; ++cx) {
                        float wx = (cx == 0) ? Xw0 : (cx == 1) ? Xw1
                                 : (cx == 2) ? Xw2 : Xw3;
                        float wgt = wy * wx;
                        if (wgt != 0.0f) {
                            int xx = min(xbase + cx, 33);
                            const float* t = rowp + xx * CP;
                            float4 v0 = *(const float4*)(t);
                            float4 v1 = *(const float4*)(t + 4);
                            float2 v2 = *(const float2*)(t + 8);
                            s0.x += wgt * v0.x; s0.y += wgt * v0.y;
                            s0.z += wgt * v0.z; s0.w += wgt * v0.w;
                            s1.x += wgt * v1.x; s1.y += wgt * v1.y;
                            s1.z += wgt * v1.z; s1.w += wgt * v1.w;
                            s2.x += wgt * v2.x; s2.y += wgt * v2.y;
                        }
                    }
                }
            }

            float cnt = cntx * cnty;
            if (!(cnt > 0.0f)) cnt = 1.0f;
            float inv = 1.0f / cnt;

            // Stage to LDS [n_loc][c*49+p]: 16 lanes stride-490 (==10 mod 32)
            // per c -> 2-way max, effectively conflict-free.
            float* __restrict__ ol = olds + n_loc * R + p;
            ol[0 * P] = s0.x * inv;  ol[1 * P] = s0.y * inv;
            ol[2 * P] = s0.z * inv;  ol[3 * P] = s0.w * inv;
            ol[4 * P] = s1.x * inv;  ol[5 * P] = s1.y * inv;
            ol[6 * P] = s1.z * inv;  ol[7 * P] = s1.w * inv;
            ol[8 * P] = s2.x * inv;  ol[9 * P] = s2.y * inv;
        }
    }

    __syncthreads();

    // Contiguous coalesced writeout: 16 n x 490 = 31360B = 1960 float4.
    float4* __restrict__ dst4 = (float4*)(out + (size_t)n0 * R);
    const float4* __restrict__ src4 = (const float4*)olds;
    for (int i = threadIdx.x; i < (NB * R) / 4; i += 256)
        dst4[i] = src4[i];
}

// ---- fallback (no ws): R4's LDS-slab kernel with direct strided writes ----
__global__ __launch_bounds__(512, 4) void dfmb_phase1_direct(
    const float* __restrict__ ft,
    const float* __restrict__ rois,
    float* __restrict__ dst,
    int N)
{
    __shared__ float tile[HW * CP];
    const int p  = blockIdx.y;
    const int ph = p / PW;
    const int pw = p - ph * PW;
    const float* __restrict__ src = ft + p * HW;
    for (int i = threadIdx.x; i < C * HW; i += 512) {
        int c = i / HW;
        int r = i - c * HW;
        tile[r * CP + c] = src[c * FT_C_STRIDE + r];
    }
    __syncthreads();
    const int n = blockIdx.x * 512 + threadIdx.x;
    if (n >= N) return;
    float wstart, hstart, sub_w, sub_h;
    {
#pragma clang fp contract(off)
        const float inv_stride = 0.0625f;
        float rsw = rois[n * 5 + 1] * inv_stride;
        float rsh = rois[n * 5 + 2] * inv_stride;
        float rew = rois[n * 5 + 3] * inv_stride;
        float reh = rois[n * 5 + 4] * inv_stride;
        float roi_h = reh - rsh; if (!(roi_h > 0.1f)) roi_h = 0.1f;
        float roi_w = rew - rsw; if (!(roi_w > 0.1f)) roi_w = 0.1f;
        float bin_h = roi_h / 7.0f;
        float bin_w = roi_w / 7.0f;
        sub_h = bin_h * 0.25f;
        sub_w = bin_w * 0.25f;
        hstart = floorf(rsh + (float)ph * bin_h);
        wstart = floorf(rsw + (float)pw * bin_w);
    }
    float Xw[4] = {0,0,0,0}, Yw[4] = {0,0,0,0};
    float cntx = 0.f, cnty = 0.f;
    int xbase = 0, ybase = 0;
#pragma unroll
    for (int iw = 0; iw < 4; ++iw) {
        float w;
        {
#pragma clang fp contract(off)
            w = wstart + ((float)iw + 0.5f) * sub_w;
        }
        float kw  = (w > -1.0f && w < 34.0f) ? 1.0f : 0.0f;
        float x1f = floorf(w), x2f = ceilf(w);
        float x1v = (x1f >= 0.0f && x1f < 34.0f) ? 1.0f : 0.0f;
        float x2v = (x2f >= 0.0f && x2f < 34.0f) ? 1.0f : 0.0f;
        int x1 = (int)fminf(fmaxf(x1f, 0.0f), 33.0f);
        int x2 = (int)fminf(fmaxf(x2f, 0.0f), 33.0f);
        float dx = w - (float)x1;
        if (iw == 0) xbase = x1;
        Xw[x1 - xbase] += kw * (1.0f - dx) * x1v;
        Xw[x2 - xbase] += kw * dx * x2v;
        cntx += kw;
    }
#pragma unroll
    for (int ih = 0; ih < 4; ++ih) {
        float h;
        {
#pragma clang fp contract(off)
            h = hstart + ((float)ih + 0.5f) * sub_h;
        }
        float kh  = (h > -1.0f && h < 34.0f) ? 1.0f : 0.0f;
        float y1f = floorf(h), y2f = ceilf(h);
        float y1v = (y1f >= 0.0f && y1f < 34.0f) ? 1.0f : 0.0f;
        float y2v = (y2f >= 0.0f && y2f < 34.0f) ? 1.0f : 0.0f;
        int y1 = (int)fminf(fmaxf(y1f, 0.0f), 33.0f);
        int y2 = (int)fminf(fmaxf(y2f, 0.0f), 33.0f);
        float dy = h - (float)y1;
        if (ih == 0) ybase = y1;
        Yw[y1 - ybase] += kh * (1.0f - dy) * y1v;
        Yw[y2 - ybase] += kh * dy * y2v;
        cnty += kh;
    }
    float4 s0 = {0,0,0,0}, s1 = {0,0,0,0};
    float2 s2 = {0,0};
#pragma unroll
    for (int cy = 0; cy < 4; ++cy) {
        if (Yw[cy] != 0.0f) {
            int yy = min(ybase + cy, 33);
            const float* rowp = &tile[yy * (W * CP)];
#pragma unroll
            for (int cx = 0; cx < 4; ++cx) {
                float wgt = Yw[cy] * Xw[cx];
                if (wgt != 0.0f) {
                    int xx = min(xbase + cx, 33);
                    const float* t = rowp + xx * CP;
                    float4 v0 = *(const float4*)(t);
                    float4 v1 = *(const float4*)(t + 4);
                    float2 v2 = *(const float2*)(t + 8);
                    s0.x += wgt * v0.x; s0.y += wgt * v0.y;
                    s0.z += wgt * v0.z; s0.w += wgt * v0.w;
                    s1.x += wgt * v1.x; s1.y += wgt * v1.y;
                    s1.z += wgt * v1.z; s1.w += wgt * v1.w;
                    s2.x += wgt * v2.x; s2.y += wgt * v2.y;
                }
            }
        }
    }
    float cnt = cntx * cnty;
    if (!(cnt > 0.0f)) cnt = 1.0f;
    float inv = 1.0f / cnt;
    float r[10] = { s0.x*inv, s0.y*inv, s0.z*inv, s0.w*inv,
                    s1.x*inv, s1.y*inv, s1.z*inv, s1.w*inv,
                    s2.x*inv, s2.y*inv };
    float* __restrict__ o = dst + (size_t)n * R + p;
#pragma unroll
    for (int c = 0; c < C; ++c) o[c * P] = r[c];
}

extern "C" void kernel_launch(void* const* d_in, const int* in_sizes, int n_in,
                              void* d_out, int out_size, void* d_ws, size_t ws_size,
                              hipStream_t stream) {
    const float* ft   = (const float*)d_in[0];
    const float* rois = (const float*)d_in[1];
    float* out = (float*)d_out;
    const int N = in_sizes[1] / 5;

    const size_t need = (size_t)P * HW * CP * sizeof(float); // 2.72 MB
    if (d_ws != nullptr && ws_size >= need && (N % NB) == 0) {
        float* ftT = (float*)d_ws;
        dfmb_swizzle<<<dim3(P, C), dim3(256), 0, stream>>>(ft, ftT);
        dfmb_fused<<<dim3(N / NB), dim3(256), 0, stream>>>(ftT, rois, out, N);
    } else {
        dim3 grid1((N + 511) / 512, P);
        dfmb_phase1_direct<<<grid1, dim3(512), 0, stream>>>(ft, rois, out, N);
    }
}

// Round 6
// 101.516 us; speedup vs baseline: 1.7331x; 1.0215x over previous
//
#include <hip/hip_runtime.h>

// DFMBPSROIAlign. R6: bf16 LDS-slab gather.
//  R5 post-mortem: fused global-gather was L1 scatter-issue bound (~64 cyc
//  per wave-load with 64 distinct lines) ~= 45-50us. LDS handles scatter at
//  32 banks/cyc. Enablers vs R4's slow LDS version:
//   - slab packed to bf16 [pix][12] = 27.7KB -> 5 blocks/CU (R4: 55KB, 2).
//   - footprint pixel = 3x ds_read_b64 @ 24B stride (bank spread ok) vs
//     b128+b128+b64 @ 48B stride.
//   - staging = dense contiguous uint4 copy of pre-packed ftB (conflict-free)
//     vs R4's stride-12 scatter (its 2.3e7 conflict cycles).
//  Accuracy: bf16 RNE on ft adds <=~0.01 abs (threshold 8.25e-2, was 1.56e-2).
//  Writes: blocked ws [n/64][c*49+p][n%64] + R4's proven 64-wide transpose.

constexpr int C  = 10;
constexpr int PH = 7;
constexpr int PW = 7;
constexpr int H  = 34;
constexpr int W  = 34;
constexpr int P  = PH * PW;         // 49
constexpr int HW = H * W;           // 1156
constexpr int FT_C_STRIDE = P * HW; // 56644
constexpr int SPX = 12;             // ushorts per pixel (10 ch + 2 pad), 24B
constexpr int SLAB_US = HW * SPX;   // 13872 ushorts = 27744 B
constexpr int CPAD = 12;            // fp32 fallback pad
constexpr int R  = C * P;           // 490

__device__ inline unsigned bf16rn(float f) {
    unsigned u = __float_as_uint(f);
    return (u + 0x7FFFu + ((u >> 16) & 1u)) >> 16;
}
__device__ inline float bf16lo(unsigned u) { return __uint_as_float(u << 16); }
__device__ inline float bf16hi(unsigned u) { return __uint_as_float(u & 0xFFFF0000u); }

// ---- pack ft (C,P,H,W) fp32 -> ftB[p][pix][12 bf16] ----
__global__ __launch_bounds__(256) void dfmb_pack(
    const float* __restrict__ ft, ushort* __restrict__ ftB)
{
    const int p = blockIdx.x;
    const float* __restrict__ src = ft + p * HW;
    for (int pix = threadIdx.x; pix < HW; pix += 256) {
        unsigned d[6];
#pragma unroll
        for (int k = 0; k < 5; ++k) {
            float a = src[(2 * k) * FT_C_STRIDE + pix];
            float b = src[(2 * k + 1) * FT_C_STRIDE + pix];
            d[k] = bf16rn(a) | (bf16rn(b) << 16);
        }
        d[5] = 0;
        uint2* dst = (uint2*)(ftB + (size_t)p * SLAB_US + pix * SPX);
        dst[0] = make_uint2(d[0], d[1]);
        dst[1] = make_uint2(d[2], d[3]);
        dst[2] = make_uint2(d[4], d[5]);
    }
}

// ---- main: per-part bf16 slab in LDS, separable footprint, blocked ws out ----
__global__ __launch_bounds__(256, 5) void dfmb_main(
    const ushort* __restrict__ ftB,
    const float* __restrict__ rois,
    float* __restrict__ ws,     // [n/64][c*49+p][n%64]
    int N)
{
    __shared__ ushort slab[SLAB_US];    // 27744 B

    const int p  = blockIdx.y;
    const int ph = p / PW;
    const int pw = p - ph * PW;

    // Dense conflict-free staging: 1734 uint4.
    {
        const uint4* __restrict__ s4 = (const uint4*)(ftB + (size_t)p * SLAB_US);
        uint4* d4 = (uint4*)slab;
        for (int i = threadIdx.x; i < SLAB_US / 8; i += 256) d4[i] = s4[i];
    }
    __syncthreads();

    const int n = blockIdx.x * 256 + threadIdx.x;
    if (n >= N) return;

    // Coordinate setup — contraction OFF so floor() args match the reference
    // rounding (verified passing R0-R5).
    float wstart, hstart, sub_w, sub_h;
    {
#pragma clang fp contract(off)
        const float inv_stride = 0.0625f;
        float rsw = rois[n * 5 + 1] * inv_stride;
        float rsh = rois[n * 5 + 2] * inv_stride;
        float rew = rois[n * 5 + 3] * inv_stride;
        float reh = rois[n * 5 + 4] * inv_stride;
        float roi_h = reh - rsh; if (!(roi_h > 0.1f)) roi_h = 0.1f;
        float roi_w = rew - rsw; if (!(roi_w > 0.1f)) roi_w = 0.1f;
        float bin_h = roi_h / 7.0f;
        float bin_w = roi_w / 7.0f;
        sub_h = bin_h * 0.25f;
        sub_w = bin_w * 0.25f;
        hstart = floorf(rsh + (float)ph * bin_h);
        wstart = floorf(rsw + (float)pw * bin_w);
    }

    // ---- separable 1-D weight footprints (<=4 cols x <=4 rows) ----
    float Xw0 = 0.f, Xw1 = 0.f, Xw2 = 0.f, Xw3 = 0.f, cntx = 0.f;
    int xbase = 0;
#pragma unroll
    for (int iw = 0; iw < 4; ++iw) {
        float w;
        {
#pragma clang fp contract(off)
            w = wstart + ((float)iw + 0.5f) * sub_w;
        }
        float kw  = (w > -1.0f && w < 34.0f) ? 1.0f : 0.0f;
        float x1f = floorf(w), x2f = ceilf(w);
        float x1v = (x1f >= 0.0f && x1f < 34.0f) ? 1.0f : 0.0f;
        float x2v = (x2f >= 0.0f && x2f < 34.0f) ? 1.0f : 0.0f;
        int x1 = (int)fminf(fmaxf(x1f, 0.0f), 33.0f);
        int x2 = (int)fminf(fmaxf(x2f, 0.0f), 33.0f);
        float dx = w - (float)x1;           // vs CLAMPED corner (ref semantics)
        if (iw == 0) xbase = x1;            // minimal column (w monotone in iw)
        float a = kw * (1.0f - dx) * x1v;
        float b = kw * dx * x2v;
        int i1 = x1 - xbase, i2 = x2 - xbase;
        Xw0 += (i1 == 0) ? a : 0.f;  Xw1 += (i1 == 1) ? a : 0.f;
        Xw2 += (i1 == 2) ? a : 0.f;  Xw3 += (i1 == 3) ? a : 0.f;
        Xw0 += (i2 == 0) ? b : 0.f;  Xw1 += (i2 == 1) ? b : 0.f;
        Xw2 += (i2 == 2) ? b : 0.f;  Xw3 += (i2 == 3) ? b : 0.f;
        cntx += kw;
    }

    float Yw0 = 0.f, Yw1 = 0.f, Yw2 = 0.f, Yw3 = 0.f, cnty = 0.f;
    int ybase = 0;
#pragma unroll
    for (int ih = 0; ih < 4; ++ih) {
        float h;
        {
#pragma clang fp contract(off)
            h = hstart + ((float)ih + 0.5f) * sub_h;
        }
        float kh  = (h > -1.0f && h < 34.0f) ? 1.0f : 0.0f;
        float y1f = floorf(h), y2f = ceilf(h);
        float y1v = (y1f >= 0.0f && y1f < 34.0f) ? 1.0f : 0.0f;
        float y2v = (y2f >= 0.0f && y2f < 34.0f) ? 1.0f : 0.0f;
        int y1 = (int)fminf(fmaxf(y1f, 0.0f), 33.0f);
        int y2 = (int)fminf(fmaxf(y2f, 0.0f), 33.0f);
        float dy = h - (float)y1;
        if (ih == 0) ybase = y1;
        float a = kh * (1.0f - dy) * y1v;
        float b = kh * dy * y2v;
        int i1 = y1 - ybase, i2 = y2 - ybase;
        Yw0 += (i1 == 0) ? a : 0.f;  Yw1 += (i1 == 1) ? a : 0.f;
        Yw2 += (i1 == 2) ? a : 0.f;  Yw3 += (i1 == 3) ? a : 0.f;
        Yw0 += (i2 == 0) ? b : 0.f;  Yw1 += (i2 == 1) ? b : 0.f;
        Yw2 += (i2 == 2) ? b : 0.f;  Yw3 += (i2 == 3) ? b : 0.f;
        cnty += kh;
    }

    // ---- accumulate over footprint: 3x ds_read_b64 per pixel (10 bf16 ch) ----
    float s0=0.f,s1=0.f,s2=0.f,s3=0.f,s4=0.f,s5=0.f,s6=0.f,s7=0.f,s8=0.f,s9=0.f;
#pragma unroll
    for (int cy = 0; cy < 4; ++cy) {
        float wy = (cy == 0) ? Yw0 : (cy == 1) ? Yw1 : (cy == 2) ? Yw2 : Yw3;
        if (wy != 0.0f) {
            int yy = min(ybase + cy, 33);
            const ushort* rowp = slab + yy * (W * SPX);
#pragma unroll
            for (int cx = 0; cx < 4; ++cx) {
                float wx = (cx == 0) ? Xw0 : (cx == 1) ? Xw1
                         : (cx == 2) ? Xw2 : Xw3;
                float wgt = wy * wx;
                if (wgt != 0.0f) {
                    int xx = min(xbase + cx, 33);
                    const uint2* t = (const uint2*)(rowp + xx * SPX);
                    uint2 a = t[0], b = t[1], c2 = t[2];
                    s0 += wgt * bf16lo(a.x);  s1 += wgt * bf16hi(a.x);
                    s2 += wgt * bf16lo(a.y);  s3 += wgt * bf16hi(a.y);
                    s4 += wgt * bf16lo(b.x);  s5 += wgt * bf16hi(b.x);
                    s6 += wgt * bf16lo(b.y);  s7 += wgt * bf16hi(b.y);
                    s8 += wgt * bf16lo(c2.x); s9 += wgt * bf16hi(c2.x);
                }
            }
        }
    }

    float cnt = cntx * cnty;
    if (!(cnt > 0.0f)) cnt = 1.0f;
    float inv = 1.0f / cnt;
    float r[10] = { s0*inv, s1*inv, s2*inv, s3*inv, s4*inv,
                    s5*inv, s6*inv, s7*inv, s8*inv, s9*inv };

    // Blocked coalesced writes: 64 lanes consecutive n -> 256B runs.
    float* __restrict__ o = ws + (size_t)(n >> 6) * (R * 64)
                               + (size_t)p * 64 + (n & 63);
#pragma unroll
    for (int c = 0; c < C; ++c) o[(size_t)(c * P) * 64] = r[c];
}

// Per-block contiguous transpose: ws[nblk][r][nl] -> out[n][r]. (R4, ~roofline)
constexpr int TR = 245;
__global__ __launch_bounds__(1024) void dfmb_phase2(
    const float* __restrict__ ws, float* __restrict__ out, int N)
{
    __shared__ float t[TR * 65];    // 63700 B
    const int nblk = blockIdx.x;
    const int r0   = blockIdx.y * TR;
    const float* __restrict__ srcb = ws + (size_t)nblk * (R * 64) + (size_t)r0 * 64;

    for (int i = threadIdx.x; i < TR * 16; i += 1024) {
        int rr  = i >> 4;
        int nl4 = (i & 15) * 4;
        float4 v = ((const float4*)srcb)[i];
        float* tp = &t[rr * 65 + nl4];
        tp[0] = v.x; tp[1] = v.y; tp[2] = v.z; tp[3] = v.w;
    }
    __syncthreads();

    const int n0 = nblk * 64;
    for (int i = threadIdx.x; i < 64 * TR; i += 1024) {
        int nl = i / TR;
        int r  = i - nl * TR;
        out[(size_t)(n0 + nl) * R + r0 + r] = t[r * 65 + nl];
    }
}

// ---- fallback (no ws): R4's fp32 LDS-slab kernel, direct strided writes ----
__global__ __launch_bounds__(512, 4) void dfmb_phase1_direct(
    const float* __restrict__ ft,
    const float* __restrict__ rois,
    float* __restrict__ dst,
    int N)
{
    __shared__ float tile[HW * CPAD];
    const int p  = blockIdx.y;
    const int ph = p / PW;
    const int pw = p - ph * PW;
    const float* __restrict__ src = ft + p * HW;
    for (int i = threadIdx.x; i < C * HW; i += 512) {
        int c = i / HW;
        int r = i - c * HW;
        tile[r * CPAD + c] = src[c * FT_C_STRIDE + r];
    }
    __syncthreads();
    const int n = blockIdx.x * 512 + threadIdx.x;
    if (n >= N) return;
    float wstart, hstart, sub_w, sub_h;
    {
#pragma clang fp contract(off)
        const float inv_stride = 0.0625f;
        float rsw = rois[n * 5 + 1] * inv_stride;
        float rsh = rois[n * 5 + 2] * inv_stride;
        float rew = rois[n * 5 + 3] * inv_stride;
        float reh = rois[n * 5 + 4] * inv_stride;
        float roi_h = reh - rsh; if (!(roi_h > 0.1f)) roi_h = 0.1f;
        float roi_w = rew - rsw; if (!(roi_w > 0.1f)) roi_w = 0.1f;
        float bin_h = roi_h / 7.0f;
        float bin_w = roi_w / 7.0f;
        sub_h = bin_h * 0.25f;
        sub_w = bin_w * 0.25f;
        hstart = floorf(rsh + (float)ph * bin_h);
        wstart = floorf(rsw + (float)pw * bin_w);
    }
    float Xw0=0.f,Xw1=0.f,Xw2=0.f,Xw3=0.f,cntx=0.f;
    float Yw0=0.f,Yw1=0.f,Yw2=0.f,Yw3=0.f,cnty=0.f;
    int xbase = 0, ybase = 0;
#pragma unroll
    for (int iw = 0; iw < 4; ++iw) {
        float w;
        {
#pragma clang fp contract(off)
            w = wstart + ((float)iw + 0.5f) * sub_w;
        }
        float kw  = (w > -1.0f && w < 34.0f) ? 1.0f : 0.0f;
        float x1f = floorf(w), x2f = ceilf(w);
        float x1v = (x1f >= 0.0f && x1f < 34.0f) ? 1.0f : 0.0f;
        float x2v = (x2f >= 0.0f && x2f < 34.0f) ? 1.0f : 0.0f;
        int x1 = (int)fminf(fmaxf(x1f, 0.0f), 33.0f);
        int x2 = (int)fminf(fmaxf(x2f, 0.0f), 33.0f);
        float dx = w - (float)x1;
        if (iw == 0) xbase = x1;
        float a = kw * (1.0f - dx) * x1v;
        float b = kw * dx * x2v;
        int i1 = x1 - xbase, i2 = x2 - xbase;
        Xw0 += (i1==0)?a:0.f; Xw1 += (i1==1)?a:0.f; Xw2 += (i1==2)?a:0.f; Xw3 += (i1==3)?a:0.f;
        Xw0 += (i2==0)?b:0.f; Xw1 += (i2==1)?b:0.f; Xw2 += (i2==2)?b:0.f; Xw3 += (i2==3)?b:0.f;
        cntx += kw;
    }
#pragma unroll
    for (int ih = 0; ih < 4; ++ih) {
        float h;
        {
#pragma clang fp contract(off)
            h = hstart + ((float)ih + 0.5f) * sub_h;
        }
        float kh  = (h > -1.0f && h < 34.0f) ? 1.0f : 0.0f;
        float y1f = floorf(h), y2f = ceilf(h);
        float y1v = (y1f >= 0.0f && y1f < 34.0f) ? 1.0f : 0.0f;
        float y2v = (y2f >= 0.0f && y2f < 34.0f) ? 1.0f : 0.0f;
        int y1 = (int)fminf(fmaxf(y1f, 0.0f), 33.0f);
        int y2 = (int)fminf(fmaxf(y2f, 0.0f), 33.0f);
        float dy = h - (float)y1;
        if (ih == 0) ybase = y1;
        float a = kh * (1.0f - dy) * y1v;
        float b = kh * dy * y2v;
        int i1 = y1 - ybase, i2 = y2 - ybase;
        Yw0 += (i1==0)?a:0.f; Yw1 += (i1==1)?a:0.f; Yw2 += (i1==2)?a:0.f; Yw3 += (i1==3)?a:0.f;
        Yw0 += (i2==0)?b:0.f; Yw1 += (i2==1)?b:0.f; Yw2 += (i2==2)?b:0.f; Yw3 += (i2==3)?b:0.f;
        cnty += kh;
    }
    float4 v0s = {0,0,0,0}, v1s = {0,0,0,0};
    float2 v2s = {0,0};
#pragma unroll
    for (int cy = 0; cy < 4; ++cy) {
        float wy = (cy==0)?Yw0:(cy==1)?Yw1:(cy==2)?Yw2:Yw3;
        if (wy != 0.0f) {
            int yy = min(ybase + cy, 33);
            const float* rowp = &tile[yy * (W * CPAD)];
#pragma unroll
            for (int cx = 0; cx < 4; ++cx) {
                float wx = (cx==0)?Xw0:(cx==1)?Xw1:(cx==2)?Xw2:Xw3;
                float wgt = wy * wx;
                if (wgt != 0.0f) {
                    int xx = min(xbase + cx, 33);
                    const float* t = rowp + xx * CPAD;
                    float4 a = *(const float4*)(t);
                    float4 b = *(const float4*)(t + 4);
                    float2 c2 = *(const float2*)(t + 8);
                    v0s.x += wgt*a.x; v0s.y += wgt*a.y; v0s.z += wgt*a.z; v0s.w += wgt*a.w;
                    v1s.x += wgt*b.x; v1s.y += wgt*b.y; v1s.z += wgt*b.z; v1s.w += wgt*b.w;
                    v2s.x += wgt*c2.x; v2s.y += wgt*c2.y;
                }
            }
        }
    }
    float cnt = cntx * cnty;
    if (!(cnt > 0.0f)) cnt = 1.0f;
    float inv = 1.0f / cnt;
    float r[10] = { v0s.x*inv, v0s.y*inv, v0s.z*inv, v0s.w*inv,
                    v1s.x*inv, v1s.y*inv, v1s.z*inv, v1s.w*inv,
                    v2s.x*inv, v2s.y*inv };
    float* __restrict__ o = dst + (size_t)n * R + p;
#pragma unroll
    for (int c = 0; c < C; ++c) o[c * P] = r[c];
}

extern "C" void kernel_launch(void* const* d_in, const int* in_sizes, int n_in,
                              void* d_out, int out_size, void* d_ws, size_t ws_size,
                              hipStream_t stream) {
    const float* ft   = (const float*)d_in[0];
    const float* rois = (const float*)d_in[1];
    float* out = (float*)d_out;
    const int N = in_sizes[1] / 5;

    const size_t packB = (size_t)P * SLAB_US * sizeof(ushort); // 1.36 MB
    const size_t wsOff = (packB + 255) & ~(size_t)255;
    const size_t need  = wsOff + (size_t)R * N * sizeof(float);
    if (d_ws != nullptr && ws_size >= need && (N % 256) == 0) {
        ushort* ftB = (ushort*)d_ws;
        float*  ws2 = (float*)((char*)d_ws + wsOff);
        dfmb_pack<<<dim3(P), dim3(256), 0, stream>>>(ft, ftB);
        dfmb_main<<<dim3(N / 256, P), dim3(256), 0, stream>>>(ftB, rois, ws2, N);
        dfmb_phase2<<<dim3(N / 64, 2), dim3(1024), 0, stream>>>(ws2, out, N);
    } else {
        dim3 grid1((N + 511) / 512, P);
        dfmb_phase1_direct<<<grid1, dim3(512), 0, stream>>>(ft, rois, out, N);
    }
}

// Round 7
// 99.758 us; speedup vs baseline: 1.7636x; 1.0176x over previous
//
#include <hip/hip_runtime.h>

// DFMBPSROIAlign. R7: bf16 intermediate.
//  R6 post-mortem: ~58us of the 101.5 is harness poison/restore floor
//  (256MiB ws fill ~48us + 32MB out fill ~6us + restores). Of our ~43us,
//  the ws round-trip (64MB, L2-cold after the poison flush) dominates.
//  R7 packs the 10 per-(n,p) results into 5 bf16-pair uints: ws shrinks
//  32->16MB (main stores halved, phase2 reads halved); phase2 becomes one
//  contiguous 62.7KB tile per 64-n slab. bf16 RNE on results adds <=0.008
//  abs (absmax 0.031 -> ~0.04, threshold 0.0825).

constexpr int C  = 10;
constexpr int PH = 7;
constexpr int PW = 7;
constexpr int H  = 34;
constexpr int W  = 34;
constexpr int P  = PH * PW;         // 49
constexpr int HW = H * W;           // 1156
constexpr int FT_C_STRIDE = P * HW; // 56644
constexpr int SPX = 12;             // ushorts per pixel (10 ch + 2 pad), 24B
constexpr int SLAB_US = HW * SPX;   // 13872 ushorts = 27744 B
constexpr int CPAD = 12;            // fp32 fallback pad
constexpr int R  = C * P;           // 490
constexpr int RU = (C / 2) * P;     // 245 uint rows (bf16 channel pairs)

__device__ inline unsigned bf16rn(float f) {
    unsigned u = __float_as_uint(f);
    return (u + 0x7FFFu + ((u >> 16) & 1u)) >> 16;
}
__device__ inline float bf16lo(unsigned u) { return __uint_as_float(u << 16); }
__device__ inline float bf16hi(unsigned u) { return __uint_as_float(u & 0xFFFF0000u); }

// ---- pack ft (C,P,H,W) fp32 -> ftB[p][pix][12 bf16] ----
__global__ __launch_bounds__(256) void dfmb_pack(
    const float* __restrict__ ft, ushort* __restrict__ ftB)
{
    const int p = blockIdx.x;
    const float* __restrict__ src = ft + p * HW;
    for (int pix = threadIdx.x; pix < HW; pix += 256) {
        unsigned d[6];
#pragma unroll
        for (int k = 0; k < 5; ++k) {
            float a = src[(2 * k) * FT_C_STRIDE + pix];
            float b = src[(2 * k + 1) * FT_C_STRIDE + pix];
            d[k] = bf16rn(a) | (bf16rn(b) << 16);
        }
        d[5] = 0;
        uint2* dst = (uint2*)(ftB + (size_t)p * SLAB_US + pix * SPX);
        dst[0] = make_uint2(d[0], d[1]);
        dst[1] = make_uint2(d[2], d[3]);
        dst[2] = make_uint2(d[4], d[5]);
    }
}

// ---- main: bf16 LDS slab gather, bf16-pair packed blocked ws out ----
__global__ __launch_bounds__(256, 5) void dfmb_main(
    const ushort* __restrict__ ftB,
    const float* __restrict__ rois,
    unsigned* __restrict__ ws,  // [n/64][c2*49+p][n%64] bf16 pairs
    int N)
{
    __shared__ ushort slab[SLAB_US];    // 27744 B

    const int p  = blockIdx.y;
    const int ph = p / PW;
    const int pw = p - ph * PW;

    // Dense conflict-free staging: 1734 uint4.
    {
        const uint4* __restrict__ s4 = (const uint4*)(ftB + (size_t)p * SLAB_US);
        uint4* d4 = (uint4*)slab;
        for (int i = threadIdx.x; i < SLAB_US / 8; i += 256) d4[i] = s4[i];
    }
    __syncthreads();

    const int n = blockIdx.x * 256 + threadIdx.x;
    if (n >= N) return;

    // Coordinate setup — contraction OFF so floor() args match the reference
    // rounding (verified passing R0-R6).
    float wstart, hstart, sub_w, sub_h;
    {
#pragma clang fp contract(off)
        const float inv_stride = 0.0625f;
        float rsw = rois[n * 5 + 1] * inv_stride;
        float rsh = rois[n * 5 + 2] * inv_stride;
        float rew = rois[n * 5 + 3] * inv_stride;
        float reh = rois[n * 5 + 4] * inv_stride;
        float roi_h = reh - rsh; if (!(roi_h > 0.1f)) roi_h = 0.1f;
        float roi_w = rew - rsw; if (!(roi_w > 0.1f)) roi_w = 0.1f;
        float bin_h = roi_h / 7.0f;
        float bin_w = roi_w / 7.0f;
        sub_h = bin_h * 0.25f;
        sub_w = bin_w * 0.25f;
        hstart = floorf(rsh + (float)ph * bin_h);
        wstart = floorf(rsw + (float)pw * bin_w);
    }

    // ---- separable 1-D weight footprints (<=4 cols x <=4 rows) ----
    float Xw0 = 0.f, Xw1 = 0.f, Xw2 = 0.f, Xw3 = 0.f, cntx = 0.f;
    int xbase = 0;
#pragma unroll
    for (int iw = 0; iw < 4; ++iw) {
        float w;
        {
#pragma clang fp contract(off)
            w = wstart + ((float)iw + 0.5f) * sub_w;
        }
        float kw  = (w > -1.0f && w < 34.0f) ? 1.0f : 0.0f;
        float x1f = floorf(w), x2f = ceilf(w);
        float x1v = (x1f >= 0.0f && x1f < 34.0f) ? 1.0f : 0.0f;
        float x2v = (x2f >= 0.0f && x2f < 34.0f) ? 1.0f : 0.0f;
        int x1 = (int)fminf(fmaxf(x1f, 0.0f), 33.0f);
        int x2 = (int)fminf(fmaxf(x2f, 0.0f), 33.0f);
        float dx = w - (float)x1;           // vs CLAMPED corner (ref semantics)
        if (iw == 0) xbase = x1;            // minimal column (w monotone in iw)
        float a = kw * (1.0f - dx) * x1v;
        float b = kw * dx * x2v;
        int i1 = x1 - xbase, i2 = x2 - xbase;
        Xw0 += (i1 == 0) ? a : 0.f;  Xw1 += (i1 == 1) ? a : 0.f;
        Xw2 += (i1 == 2) ? a : 0.f;  Xw3 += (i1 == 3) ? a : 0.f;
        Xw0 += (i2 == 0) ? b : 0.f;  Xw1 += (i2 == 1) ? b : 0.f;
        Xw2 += (i2 == 2) ? b : 0.f;  Xw3 += (i2 == 3) ? b : 0.f;
        cntx += kw;
    }

    float Yw0 = 0.f, Yw1 = 0.f, Yw2 = 0.f, Yw3 = 0.f, cnty = 0.f;
    int ybase = 0;
#pragma unroll
    for (int ih = 0; ih < 4; ++ih) {
        float h;
        {
#pragma clang fp contract(off)
            h = hstart + ((float)ih + 0.5f) * sub_h;
        }
        float kh  = (h > -1.0f && h < 34.0f) ? 1.0f : 0.0f;
        float y1f = floorf(h), y2f = ceilf(h);
        float y1v = (y1f >= 0.0f && y1f < 34.0f) ? 1.0f : 0.0f;
        float y2v = (y2f >= 0.0f && y2f < 34.0f) ? 1.0f : 0.0f;
        int y1 = (int)fminf(fmaxf(y1f, 0.0f), 33.0f);
        int y2 = (int)fminf(fmaxf(y2f, 0.0f), 33.0f);
        float dy = h - (float)y1;
        if (ih == 0) ybase = y1;
        float a = kh * (1.0f - dy) * y1v;
        float b = kh * dy * y2v;
        int i1 = y1 - ybase, i2 = y2 - ybase;
        Yw0 += (i1 == 0) ? a : 0.f;  Yw1 += (i1 == 1) ? a : 0.f;
        Yw2 += (i1 == 2) ? a : 0.f;  Yw3 += (i1 == 3) ? a : 0.f;
        Yw0 += (i2 == 0) ? b : 0.f;  Yw1 += (i2 == 1) ? b : 0.f;
        Yw2 += (i2 == 2) ? b : 0.f;  Yw3 += (i2 == 3) ? b : 0.f;
        cnty += kh;
    }

    // ---- accumulate over footprint: 3x ds_read_b64 per pixel ----
    float s0=0.f,s1=0.f,s2=0.f,s3=0.f,s4=0.f,s5=0.f,s6=0.f,s7=0.f,s8=0.f,s9=0.f;
#pragma unroll
    for (int cy = 0; cy < 4; ++cy) {
        float wy = (cy == 0) ? Yw0 : (cy == 1) ? Yw1 : (cy == 2) ? Yw2 : Yw3;
        if (wy != 0.0f) {
            int yy = min(ybase + cy, 33);
            const ushort* rowp = slab + yy * (W * SPX);
#pragma unroll
            for (int cx = 0; cx < 4; ++cx) {
                float wx = (cx == 0) ? Xw0 : (cx == 1) ? Xw1
                         : (cx == 2) ? Xw2 : Xw3;
                float wgt = wy * wx;
                if (wgt != 0.0f) {
                    int xx = min(xbase + cx, 33);
                    const uint2* t = (const uint2*)(rowp + xx * SPX);
                    uint2 a = t[0], b = t[1], c2 = t[2];
                    s0 += wgt * bf16lo(a.x);  s1 += wgt * bf16hi(a.x);
                    s2 += wgt * bf16lo(a.y);  s3 += wgt * bf16hi(a.y);
                    s4 += wgt * bf16lo(b.x);  s5 += wgt * bf16hi(b.x);
                    s6 += wgt * bf16lo(b.y);  s7 += wgt * bf16hi(b.y);
                    s8 += wgt * bf16lo(c2.x); s9 += wgt * bf16hi(c2.x);
                }
            }
        }
    }

    float cnt = cntx * cnty;
    if (!(cnt > 0.0f)) cnt = 1.0f;
    float inv = 1.0f / cnt;

    // Pack 10 results into 5 bf16-pair uints; blocked coalesced stores.
    unsigned r01 = bf16rn(s0 * inv) | (bf16rn(s1 * inv) << 16);
    unsigned r23 = bf16rn(s2 * inv) | (bf16rn(s3 * inv) << 16);
    unsigned r45 = bf16rn(s4 * inv) | (bf16rn(s5 * inv) << 16);
    unsigned r67 = bf16rn(s6 * inv) | (bf16rn(s7 * inv) << 16);
    unsigned r89 = bf16rn(s8 * inv) | (bf16rn(s9 * inv) << 16);

    unsigned* __restrict__ o = ws + (size_t)(n >> 6) * (RU * 64)
                                  + (size_t)p * 64 + (n & 63);
    o[0 * (P * 64)] = r01;
    o[1 * (P * 64)] = r23;
    o[2 * (P * 64)] = r45;
    o[3 * (P * 64)] = r67;
    o[4 * (P * 64)] = r89;
}

// Per-64n-slab transpose+unpack: ws[nblk][c2*49+p][nl] (245x64 uints,
// contiguous 62.7KB) -> out[n][c*49+p] fp32. 65-pad tile: conflict-free.
__global__ __launch_bounds__(1024) void dfmb_phase2(
    const unsigned* __restrict__ ws, float* __restrict__ out, int N)
{
    __shared__ unsigned t[RU * 65];     // 63700 B
    const int nblk = blockIdx.x;
    const unsigned* __restrict__ srcb = ws + (size_t)nblk * (RU * 64);

    // Load 245 rows x 64 nl contiguous via uint4 (3920 of them).
    for (int i = threadIdx.x; i < RU * 16; i += 1024) {
        int rr  = i >> 4;
        int nl4 = (i & 15) * 4;
        uint4 v = ((const uint4*)srcb)[i];
        unsigned* tp = &t[rr * 65 + nl4];
        tp[0] = v.x; tp[1] = v.y; tp[2] = v.z; tp[3] = v.w;
    }
    __syncthreads();

    // Write out[n0+nl][r]: lane-consecutive r -> coalesced 256B.
    const int n0 = nblk * 64;
    for (int j = threadIdx.x; j < 64 * R; j += 1024) {
        int nl = j / R;
        int r  = j - nl * R;
        int c  = r / P;                 // magic-mul (const 49)
        int pp = r - c * P;
        unsigned u = t[((c >> 1) * P + pp) * 65 + nl];
        out[(size_t)(n0 + nl) * R + r] = (c & 1) ? bf16hi(u) : bf16lo(u);
    }
}

// ---- fallback (no ws): fp32 LDS-slab kernel, direct strided writes ----
__global__ __launch_bounds__(512, 4) void dfmb_phase1_direct(
    const float* __restrict__ ft,
    const float* __restrict__ rois,
    float* __restrict__ dst,
    int N)
{
    __shared__ float tile[HW * CPAD];
    const int p  = blockIdx.y;
    const int ph = p / PW;
    const int pw = p - ph * PW;
    const float* __restrict__ src = ft + p * HW;
    for (int i = threadIdx.x; i < C * HW; i += 512) {
        int c = i / HW;
        int r = i - c * HW;
        tile[r * CPAD + c] = src[c * FT_C_STRIDE + r];
    }
    __syncthreads();
    const int n = blockIdx.x * 512 + threadIdx.x;
    if (n >= N) return;
    float wstart, hstart, sub_w, sub_h;
    {
#pragma clang fp contract(off)
        const float inv_stride = 0.0625f;
        float rsw = rois[n * 5 + 1] * inv_stride;
        float rsh = rois[n * 5 + 2] * inv_stride;
        float rew = rois[n * 5 + 3] * inv_stride;
        float reh = rois[n * 5 + 4] * inv_stride;
        float roi_h = reh - rsh; if (!(roi_h > 0.1f)) roi_h = 0.1f;
        float roi_w = rew - rsw; if (!(roi_w > 0.1f)) roi_w = 0.1f;
        float bin_h = roi_h / 7.0f;
        float bin_w = roi_w / 7.0f;
        sub_h = bin_h * 0.25f;
        sub_w = bin_w * 0.25f;
        hstart = floorf(rsh + (float)ph * bin_h);
        wstart = floorf(rsw + (float)pw * bin_w);
    }
    float Xw0=0.f,Xw1=0.f,Xw2=0.f,Xw3=0.f,cntx=0.f;
    float Yw0=0.f,Yw1=0.f,Yw2=0.f,Yw3=0.f,cnty=0.f;
    int xbase = 0, ybase = 0;
#pragma unroll
    for (int iw = 0; iw < 4; ++iw) {
        float w;
        {
#pragma clang fp contract(off)
            w = wstart + ((float)iw + 0.5f) * sub_w;
        }
        float kw  = (w > -1.0f && w < 34.0f) ? 1.0f : 0.0f;
        float x1f = floorf(w), x2f = ceilf(w);
        float x1v = (x1f >= 0.0f && x1f < 34.0f) ? 1.0f : 0.0f;
        float x2v = (x2f >= 0.0f && x2f < 34.0f) ? 1.0f : 0.0f;
        int x1 = (int)fminf(fmaxf(x1f, 0.0f), 33.0f);
        int x2 = (int)fminf(fmaxf(x2f, 0.0f), 33.0f);
        float dx = w - (float)x1;
        if (iw == 0) xbase = x1;
        float a = kw * (1.0f - dx) * x1v;
        float b = kw * dx * x2v;
        int i1 = x1 - xbase, i2 = x2 - xbase;
        Xw0 += (i1==0)?a:0.f; Xw1 += (i1==1)?a:0.f; Xw2 += (i1==2)?a:0.f; Xw3 += (i1==3)?a:0.f;
        Xw0 += (i2==0)?b:0.f; Xw1 += (i2==1)?b:0.f; Xw2 += (i2==2)?b:0.f; Xw3 += (i2==3)?b:0.f;
        cntx += kw;
    }
#pragma unroll
    for (int ih = 0; ih < 4; ++ih) {
        float h;
        {
#pragma clang fp contract(off)
            h = hstart + ((float)ih + 0.5f) * sub_h;
        }
        float kh  = (h > -1.0f && h < 34.0f) ? 1.0f : 0.0f;
        float y1f = floorf(h), y2f = ceilf(h);
        float y1v = (y1f >= 0.0f && y1f < 34.0f) ? 1.0f : 0.0f;
        float y2v = (y2f >= 0.0f && y2f < 34.0f) ? 1.0f : 0.0f;
        int y1 = (int)fminf(fmaxf(y1f, 0.0f), 33.0f);
        int y2 = (int)fminf(fmaxf(y2f, 0.0f), 33.0f);
        float dy = h - (float)y1;
        if (ih == 0) ybase = y1;
        float a = kh * (1.0f - dy) * y1v;
        float b = kh * dy * y2v;
        int i1 = y1 - ybase, i2 = y2 - ybase;
        Yw0 += (i1==0)?a:0.f; Yw1 += (i1==1)?a:0.f; Yw2 += (i1==2)?a:0.f; Yw3 += (i1==3)?a:0.f;
        Yw0 += (i2==0)?b:0.f; Yw1 += (i2==1)?b:0.f; Yw2 += (i2==2)?b:0.f; Yw3 += (i2==3)?b:0.f;
        cnty += kh;
    }
    float4 v0s = {0,0,0,0}, v1s = {0,0,0,0};
    float2 v2s = {0,0};
#pragma unroll
    for (int cy = 0; cy < 4; ++cy) {
        float wy = (cy==0)?Yw0:(cy==1)?Yw1:(cy==2)?Yw2:Yw3;
        if (wy != 0.0f) {
            int yy = min(ybase + cy, 33);
            const float* rowp = &tile[yy * (W * CPAD)];
#pragma unroll
            for (int cx = 0; cx < 4; ++cx) {
                float wx = (cx==0)?Xw0:(cx==1)?Xw1:(cx==2)?Xw2:Xw3;
                float wgt = wy * wx;
                if (wgt != 0.0f) {
                    int xx = min(xbase + cx, 33);
                    const float* t = rowp + xx * CPAD;
                    float4 a = *(const float4*)(t);
                    float4 b = *(const float4*)(t + 4);
                    float2 c2 = *(const float2*)(t + 8);
                    v0s.x += wgt*a.x; v0s.y += wgt*a.y; v0s.z += wgt*a.z; v0s.w += wgt*a.w;
                    v1s.x += wgt*b.x; v1s.y += wgt*b.y; v1s.z += wgt*b.z; v1s.w += wgt*b.w;
                    v2s.x += wgt*c2.x; v2s.y += wgt*c2.y;
                }
            }
        }
    }
    float cnt = cntx * cnty;
    if (!(cnt > 0.0f)) cnt = 1.0f;
    float inv = 1.0f / cnt;
    float r[10] = { v0s.x*inv, v0s.y*inv, v0s.z*inv, v0s.w*inv,
                    v1s.x*inv, v1s.y*inv, v1s.z*inv, v1s.w*inv,
                    v2s.x*inv, v2s.y*inv };
    float* __restrict__ o = dst + (size_t)n * R + p;
#pragma unroll
    for (int c = 0; c < C; ++c) o[c * P] = r[c];
}

extern "C" void kernel_launch(void* const* d_in, const int* in_sizes, int n_in,
                              void* d_out, int out_size, void* d_ws, size_t ws_size,
                              hipStream_t stream) {
    const float* ft   = (const float*)d_in[0];
    const float* rois = (const float*)d_in[1];
    float* out = (float*)d_out;
    const int N = in_sizes[1] / 5;

    const size_t packB = (size_t)P * SLAB_US * sizeof(ushort); // 1.36 MB
    const size_t wsOff = (packB + 255) & ~(size_t)255;
    const size_t need  = wsOff + (size_t)RU * N * sizeof(unsigned); // +16 MB
    if (d_ws != nullptr && ws_size >= need && (N % 256) == 0) {
        ushort*   ftB = (ushort*)d_ws;
        unsigned* ws2 = (unsigned*)((char*)d_ws + wsOff);
        dfmb_pack<<<dim3(P), dim3(256), 0, stream>>>(ft, ftB);
        dfmb_main<<<dim3(N / 256, P), dim3(256), 0, stream>>>(ftB, rois, ws2, N);
        dfmb_phase2<<<dim3(N / 64), dim3(1024), 0, stream>>>(ws2, out, N);
    } else {
        dim3 grid1((N + 511) / 512, P);
        dfmb_phase1_direct<<<grid1, dim3(512), 0, stream>>>(ft, rois, out, N);
    }
}

// Round 8
// 96.114 us; speedup vs baseline: 1.8305x; 1.0379x over previous
//
#include <hip/hip_runtime.h>

// DFMBPSROIAlign. R8:
//  - pack kernel parallelized: grid (49,5)=245 blocks (R7 used 49 blocks ->
//    only 19% of CUs pulling the L2-cold 9MB ft: ~5-6us for a ~1.5us job).
//  - main: 512-thread blocks: staging traffic halves (87->43MB L2 reads),
//    staging instrs/CU halve, occupancy 20 -> 24-32 waves/CU.
//  - phase2: float2 stores (halve store issue). 48MB HBM round-trip ~9us
//    is roofline for the 2-pass structure.
//  Harness floor (256MiB ws + 32MB out poisons + restores) ~55-58us of dur.

constexpr int C  = 10;
constexpr int PH = 7;
constexpr int PW = 7;
constexpr int H  = 34;
constexpr int W  = 34;
constexpr int P  = PH * PW;         // 49
constexpr int HW = H * W;           // 1156
constexpr int FT_C_STRIDE = P * HW; // 56644
constexpr int SPX = 12;             // ushorts per pixel (10 ch + 2 pad), 24B
constexpr int SLAB_US = HW * SPX;   // 13872 ushorts = 27744 B
constexpr int CPAD = 12;            // fp32 fallback pad
constexpr int R  = C * P;           // 490
constexpr int RU = (C / 2) * P;     // 245 uint rows (bf16 channel pairs)

__device__ inline unsigned bf16rn(float f) {
    unsigned u = __float_as_uint(f);
    return (u + 0x7FFFu + ((u >> 16) & 1u)) >> 16;
}
__device__ inline float bf16lo(unsigned u) { return __uint_as_float(u << 16); }
__device__ inline float bf16hi(unsigned u) { return __uint_as_float(u & 0xFFFF0000u); }

// ---- pack ft (C,P,H,W) fp32 -> ftB[p][pix][12 bf16]; grid (49,5) ----
__global__ __launch_bounds__(256) void dfmb_pack(
    const float* __restrict__ ft, ushort* __restrict__ ftB)
{
    const int p   = blockIdx.x;
    const int pix = blockIdx.y * 256 + threadIdx.x;
    if (pix >= HW) return;
    const float* __restrict__ src = ft + p * HW;
    unsigned d[6];
#pragma unroll
    for (int k = 0; k < 5; ++k) {
        float a = src[(2 * k) * FT_C_STRIDE + pix];
        float b = src[(2 * k + 1) * FT_C_STRIDE + pix];
        d[k] = bf16rn(a) | (bf16rn(b) << 16);
    }
    d[5] = 0;
    uint2* dst = (uint2*)(ftB + (size_t)p * SLAB_US + pix * SPX);
    dst[0] = make_uint2(d[0], d[1]);
    dst[1] = make_uint2(d[2], d[3]);
    dst[2] = make_uint2(d[4], d[5]);
}

// ---- main: bf16 LDS slab gather, bf16-pair packed blocked ws out ----
__global__ __launch_bounds__(512) void dfmb_main(
    const ushort* __restrict__ ftB,
    const float* __restrict__ rois,
    unsigned* __restrict__ ws,  // [n/64][c2*49+p][n%64] bf16 pairs
    int N)
{
    __shared__ ushort slab[SLAB_US];    // 27744 B

    const int p  = blockIdx.y;
    const int ph = p / PW;
    const int pw = p - ph * PW;

    // Dense conflict-free staging: 1734 uint4 over 512 threads.
    {
        const uint4* __restrict__ s4 = (const uint4*)(ftB + (size_t)p * SLAB_US);
        uint4* d4 = (uint4*)slab;
        for (int i = threadIdx.x; i < SLAB_US / 8; i += 512) d4[i] = s4[i];
    }
    __syncthreads();

    const int n = blockIdx.x * 512 + threadIdx.x;
    if (n >= N) return;

    // Coordinate setup — contraction OFF so floor() args match the reference
    // rounding (verified passing R0-R7).
    float wstart, hstart, sub_w, sub_h;
    {
#pragma clang fp contract(off)
        const float inv_stride = 0.0625f;
        float rsw = rois[n * 5 + 1] * inv_stride;
        float rsh = rois[n * 5 + 2] * inv_stride;
        float rew = rois[n * 5 + 3] * inv_stride;
        float reh = rois[n * 5 + 4] * inv_stride;
        float roi_h = reh - rsh; if (!(roi_h > 0.1f)) roi_h = 0.1f;
        float roi_w = rew - rsw; if (!(roi_w > 0.1f)) roi_w = 0.1f;
        float bin_h = roi_h / 7.0f;
        float bin_w = roi_w / 7.0f;
        sub_h = bin_h * 0.25f;
        sub_w = bin_w * 0.25f;
        hstart = floorf(rsh + (float)ph * bin_h);
        wstart = floorf(rsw + (float)pw * bin_w);
    }

    // ---- separable 1-D weight footprints (<=4 cols x <=4 rows) ----
    float Xw0 = 0.f, Xw1 = 0.f, Xw2 = 0.f, Xw3 = 0.f, cntx = 0.f;
    int xbase = 0;
#pragma unroll
    for (int iw = 0; iw < 4; ++iw) {
        float w;
        {
#pragma clang fp contract(off)
            w = wstart + ((float)iw + 0.5f) * sub_w;
        }
        float kw  = (w > -1.0f && w < 34.0f) ? 1.0f : 0.0f;
        float x1f = floorf(w), x2f = ceilf(w);
        float x1v = (x1f >= 0.0f && x1f < 34.0f) ? 1.0f : 0.0f;
        float x2v = (x2f >= 0.0f && x2f < 34.0f) ? 1.0f : 0.0f;
        int x1 = (int)fminf(fmaxf(x1f, 0.0f), 33.0f);
        int x2 = (int)fminf(fmaxf(x2f, 0.0f), 33.0f);
        float dx = w - (float)x1;           // vs CLAMPED corner (ref semantics)
        if (iw == 0) xbase = x1;            // minimal column (w monotone in iw)
        float a = kw * (1.0f - dx) * x1v;
        float b = kw * dx * x2v;
        int i1 = x1 - xbase, i2 = x2 - xbase;
        Xw0 += (i1 == 0) ? a : 0.f;  Xw1 += (i1 == 1) ? a : 0.f;
        Xw2 += (i1 == 2) ? a : 0.f;  Xw3 += (i1 == 3) ? a : 0.f;
        Xw0 += (i2 == 0) ? b : 0.f;  Xw1 += (i2 == 1) ? b : 0.f;
        Xw2 += (i2 == 2) ? b : 0.f;  Xw3 += (i2 == 3) ? b : 0.f;
        cntx += kw;
    }

    float Yw0 = 0.f, Yw1 = 0.f, Yw2 = 0.f, Yw3 = 0.f, cnty = 0.f;
    int ybase = 0;
#pragma unroll
    for (int ih = 0; ih < 4; ++ih) {
        float h;
        {
#pragma clang fp contract(off)
            h = hstart + ((float)ih + 0.5f) * sub_h;
        }
        float kh  = (h > -1.0f && h < 34.0f) ? 1.0f : 0.0f;
        float y1f = floorf(h), y2f = ceilf(h);
        float y1v = (y1f >= 0.0f && y1f < 34.0f) ? 1.0f : 0.0f;
        float y2v = (y2f >= 0.0f && y2f < 34.0f) ? 1.0f : 0.0f;
        int y1 = (int)fminf(fmaxf(y1f, 0.0f), 33.0f);
        int y2 = (int)fminf(fmaxf(y2f, 0.0f), 33.0f);
        float dy = h - (float)y1;
        if (ih == 0) ybase = y1;
        float a = kh * (1.0f - dy) * y1v;
        float b = kh * dy * y2v;
        int i1 = y1 - ybase, i2 = y2 - ybase;
        Yw0 += (i1 == 0) ? a : 0.f;  Yw1 += (i1 == 1) ? a : 0.f;
        Yw2 += (i1 == 2) ? a : 0.f;  Yw3 += (i1 == 3) ? a : 0.f;
        Yw0 += (i2 == 0) ? b : 0.f;  Yw1 += (i2 == 1) ? b : 0.f;
        Yw2 += (i2 == 2) ? b : 0.f;  Yw3 += (i2 == 3) ? b : 0.f;
        cnty += kh;
    }

    // ---- accumulate over footprint: 3x ds_read_b64 per pixel ----
    float s0=0.f,s1=0.f,s2=0.f,s3=0.f,s4=0.f,s5=0.f,s6=0.f,s7=0.f,s8=0.f,s9=0.f;
#pragma unroll
    for (int cy = 0; cy < 4; ++cy) {
        float wy = (cy == 0) ? Yw0 : (cy == 1) ? Yw1 : (cy == 2) ? Yw2 : Yw3;
        if (wy != 0.0f) {
            int yy = min(ybase + cy, 33);
            const ushort* rowp = slab + yy * (W * SPX);
#pragma unroll
            for (int cx = 0; cx < 4; ++cx) {
                float wx = (cx == 0) ? Xw0 : (cx == 1) ? Xw1
                         : (cx == 2) ? Xw2 : Xw3;
                float wgt = wy * wx;
                if (wgt != 0.0f) {
                    int xx = min(xbase + cx, 33);
                    const uint2* t = (const uint2*)(rowp + xx * SPX);
                    uint2 a = t[0], b = t[1], c2 = t[2];
                    s0 += wgt * bf16lo(a.x);  s1 += wgt * bf16hi(a.x);
                    s2 += wgt * bf16lo(a.y);  s3 += wgt * bf16hi(a.y);
                    s4 += wgt * bf16lo(b.x);  s5 += wgt * bf16hi(b.x);
                    s6 += wgt * bf16lo(b.y);  s7 += wgt * bf16hi(b.y);
                    s8 += wgt * bf16lo(c2.x); s9 += wgt * bf16hi(c2.x);
                }
            }
        }
    }

    float cnt = cntx * cnty;
    if (!(cnt > 0.0f)) cnt = 1.0f;
    float inv = 1.0f / cnt;

    // Pack 10 results into 5 bf16-pair uints; blocked coalesced stores.
    unsigned r01 = bf16rn(s0 * inv) | (bf16rn(s1 * inv) << 16);
    unsigned r23 = bf16rn(s2 * inv) | (bf16rn(s3 * inv) << 16);
    unsigned r45 = bf16rn(s4 * inv) | (bf16rn(s5 * inv) << 16);
    unsigned r67 = bf16rn(s6 * inv) | (bf16rn(s7 * inv) << 16);
    unsigned r89 = bf16rn(s8 * inv) | (bf16rn(s9 * inv) << 16);

    unsigned* __restrict__ o = ws + (size_t)(n >> 6) * (RU * 64)
                                  + (size_t)p * 64 + (n & 63);
    o[0 * (P * 64)] = r01;
    o[1 * (P * 64)] = r23;
    o[2 * (P * 64)] = r45;
    o[3 * (P * 64)] = r67;
    o[4 * (P * 64)] = r89;
}

// Per-64n-slab transpose+unpack: ws[nblk][c2*49+p][nl] (245x64 uints,
// contiguous 62.7KB) -> out[n][c*49+p] fp32, float2 stores.
__global__ __launch_bounds__(1024) void dfmb_phase2(
    const unsigned* __restrict__ ws, float* __restrict__ out, int N)
{
    __shared__ unsigned t[RU * 65];     // 63700 B
    const int nblk = blockIdx.x;
    const unsigned* __restrict__ srcb = ws + (size_t)nblk * (RU * 64);

    // Load 245 rows x 64 nl contiguous via uint4 (3920 of them).
    for (int i = threadIdx.x; i < RU * 16; i += 1024) {
        int rr  = i >> 4;
        int nl4 = (i & 15) * 4;
        uint4 v = ((const uint4*)srcb)[i];
        unsigned* tp = &t[rr * 65 + nl4];
        tp[0] = v.x; tp[1] = v.y; tp[2] = v.z; tp[3] = v.w;
    }
    __syncthreads();

    // Write out[n0+nl][2k..2k+1]: lane-consecutive k -> coalesced 512B float2.
    const int n0 = nblk * 64;
    for (int j = threadIdx.x; j < 64 * (R / 2); j += 1024) {
        int nl = j / (R / 2);
        int k  = j - nl * (R / 2);
        int r0 = 2 * k, r1 = 2 * k + 1;
        int c0 = r0 / P, p0 = r0 - c0 * P;
        int c1 = r1 / P, p1 = r1 - c1 * P;
        unsigned u0 = t[((c0 >> 1) * P + p0) * 65 + nl];
        unsigned u1 = t[((c1 >> 1) * P + p1) * 65 + nl];
        float2 v = make_float2((c0 & 1) ? bf16hi(u0) : bf16lo(u0),
                               (c1 & 1) ? bf16hi(u1) : bf16lo(u1));
        ((float2*)(out + (size_t)(n0 + nl) * R))[k] = v;
    }
}

// ---- fallback (no ws): fp32 LDS-slab kernel, direct strided writes ----
__global__ __launch_bounds__(512, 4) void dfmb_phase1_direct(
    const float* __restrict__ ft,
    const float* __restrict__ rois,
    float* __restrict__ dst,
    int N)
{
    __shared__ float tile[HW * CPAD];
    const int p  = blockIdx.y;
    const int ph = p / PW;
    const int pw = p - ph * PW;
    const float* __restrict__ src = ft + p * HW;
    for (int i = threadIdx.x; i < C * HW; i += 512) {
        int c = i / HW;
        int r = i - c * HW;
        tile[r * CPAD + c] = src[c * FT_C_STRIDE + r];
    }
    __syncthreads();
    const int n = blockIdx.x * 512 + threadIdx.x;
    if (n >= N) return;
    float wstart, hstart, sub_w, sub_h;
    {
#pragma clang fp contract(off)
        const float inv_stride = 0.0625f;
        float rsw = rois[n * 5 + 1] * inv_stride;
        float rsh = rois[n * 5 + 2] * inv_stride;
        float rew = rois[n * 5 + 3] * inv_stride;
        float reh = rois[n * 5 + 4] * inv_stride;
        float roi_h = reh - rsh; if (!(roi_h > 0.1f)) roi_h = 0.1f;
        float roi_w = rew - rsw; if (!(roi_w > 0.1f)) roi_w = 0.1f;
        float bin_h = roi_h / 7.0f;
        float bin_w = roi_w / 7.0f;
        sub_h = bin_h * 0.25f;
        sub_w = bin_w * 0.25f;
        hstart = floorf(rsh + (float)ph * bin_h);
        wstart = floorf(rsw + (float)pw * bin_w);
    }
    float Xw0=0.f,Xw1=0.f,Xw2=0.f,Xw3=0.f,cntx=0.f;
    float Yw0=0.f,Yw1=0.f,Yw2=0.f,Yw3=0.f,cnty=0.f;
    int xbase = 0, ybase = 0;
#pragma unroll
    for (int iw = 0; iw < 4; ++iw) {
        float w;
        {
#pragma clang fp contract(off)
            w = wstart + ((float)iw + 0.5f) * sub_w;
        }
        float kw  = (w > -1.0f && w < 34.0f) ? 1.0f : 0.0f;
        float x1f = floorf(w), x2f = ceilf(w);
        float x1v = (x1f >= 0.0f && x1f < 34.0f) ? 1.0f : 0.0f;
        float x2v = (x2f >= 0.0f && x2f < 34.0f) ? 1.0f : 0.0f;
        int x1 = (int)fminf(fmaxf(x1f, 0.0f), 33.0f);
        int x2 = (int)fminf(fmaxf(x2f, 0.0f), 33.0f);
        float dx = w - (float)x1;
        if (iw == 0) xbase = x1;
        float a = kw * (1.0f - dx) * x1v;
        float b = kw * dx * x2v;
        int i1 = x1 - xbase, i2 = x2 - xbase;
        Xw0 += (i1==0)?a:0.f; Xw1 += (i1==1)?a:0.f; Xw2 += (i1==2)?a:0.f; Xw3 += (i1==3)?a:0.f;
        Xw0 += (i2==0)?b:0.f; Xw1 += (i2==1)?b:0.f; Xw2 += (i2==2)?b:0.f; Xw3 += (i2==3)?b:0.f;
        cntx += kw;
    }
#pragma unroll
    for (int ih = 0; ih < 4; ++ih) {
        float h;
        {
#pragma clang fp contract(off)
            h = hstart + ((float)ih + 0.5f) * sub_h;
        }
        float kh  = (h > -1.0f && h < 34.0f) ? 1.0f : 0.0f;
        float y1f = floorf(h), y2f = ceilf(h);
        float y1v = (y1f >= 0.0f && y1f < 34.0f) ? 1.0f : 0.0f;
        float y2v = (y2f >= 0.0f && y2f < 34.0f) ? 1.0f : 0.0f;
        int y1 = (int)fminf(fmaxf(y1f, 0.0f), 33.0f);
        int y2 = (int)fminf(fmaxf(y2f, 0.0f), 33.0f);
        float dy = h - (float)y1;
        if (ih == 0) ybase = y1;
        float a = kh * (1.0f - dy) * y1v;
        float b = kh * dy * y2v;
        int i1 = y1 - ybase, i2 = y2 - ybase;
        Yw0 += (i1==0)?a:0.f; Yw1 += (i1==1)?a:0.f; Yw2 += (i1==2)?a:0.f; Yw3 += (i1==3)?a:0.f;
        Yw0 += (i2==0)?b:0.f; Yw1 += (i2==1)?b:0.f; Yw2 += (i2==2)?b:0.f; Yw3 += (i2==3)?b:0.f;
        cnty += kh;
    }
    float4 v0s = {0,0,0,0}, v1s = {0,0,0,0};
    float2 v2s = {0,0};
#pragma unroll
    for (int cy = 0; cy < 4; ++cy) {
        float wy = (cy==0)?Yw0:(cy==1)?Yw1:(cy==2)?Yw2:Yw3;
        if (wy != 0.0f) {
            int yy = min(ybase + cy, 33);
            const float* rowp = &tile[yy * (W * CPAD)];
#pragma unroll
            for (int cx = 0; cx < 4; ++cx) {
                float wx = (cx==0)?Xw0:(cx==1)?Xw1:(cx==2)?Xw2:Xw3;
                float wgt = wy * wx;
                if (wgt != 0.0f) {
                    int xx = min(xbase + cx, 33);
                    const float* t = rowp + xx * CPAD;
                    float4 a = *(const float4*)(t);
                    float4 b = *(const float4*)(t + 4);
                    float2 c2 = *(const float2*)(t + 8);
                    v0s.x += wgt*a.x; v0s.y += wgt*a.y; v0s.z += wgt*a.z; v0s.w += wgt*a.w;
                    v1s.x += wgt*b.x; v1s.y += wgt*b.y; v1s.z += wgt*b.z; v1s.w += wgt*b.w;
                    v2s.x += wgt*c2.x; v2s.y += wgt*c2.y;
                }
            }
        }
    }
    float cnt = cntx * cnty;
    if (!(cnt > 0.0f)) cnt = 1.0f;
    float inv = 1.0f / cnt;
    float r[10] = { v0s.x*inv, v0s.y*inv, v0s.z*inv, v0s.w*inv,
                    v1s.x*inv, v1s.y*inv, v1s.z*inv, v1s.w*inv,
                    v2s.x*inv, v2s.y*inv };
    float* __restrict__ o = dst + (size_t)n * R + p;
#pragma unroll
    for (int c = 0; c < C; ++c) o[c * P] = r[c];
}

extern "C" void kernel_launch(void* const* d_in, const int* in_sizes, int n_in,
                              void* d_out, int out_size, void* d_ws, size_t ws_size,
                              hipStream_t stream) {
    const float* ft   = (const float*)d_in[0];
    const float* rois = (const float*)d_in[1];
    float* out = (float*)d_out;
    const int N = in_sizes[1] / 5;

    const size_t packB = (size_t)P * SLAB_US * sizeof(ushort); // 1.36 MB
    const size_t wsOff = (packB + 255) & ~(size_t)255;
    const size_t need  = wsOff + (size_t)RU * N * sizeof(unsigned); // +16 MB
    if (d_ws != nullptr && ws_size >= need && (N % 64) == 0) {
        ushort*   ftB = (ushort*)d_ws;
        unsigned* ws2 = (unsigned*)((char*)d_ws + wsOff);
        dfmb_pack<<<dim3(P, (HW + 255) / 256), dim3(256), 0, stream>>>(ft, ftB);
        dfmb_main<<<dim3((N + 511) / 512, P), dim3(512), 0, stream>>>(ftB, rois, ws2, N);
        dfmb_phase2<<<dim3(N / 64), dim3(1024), 0, stream>>>(ws2, out, N);
    } else {
        dim3 grid1((N + 511) / 512, P);
        dfmb_phase1_direct<<<grid1, dim3(512), 0, stream>>>(ft, rois, out, N);
    }
}

// Round 10
// 95.278 us; speedup vs baseline: 1.8465x; 1.0088x over previous
//
#include <hip/hip_runtime.h>

// DFMBPSROIAlign. R10 (= R9 with compile fix):
//  - __builtin_nontemporal_store needs a NATIVE vector type, not HIP's
//    float2 class -> use ext_vector_type(2) float.
//  - SPX 12->16 (32B/pixel): footprint pixel = ds_read_b128 + ds_read_b64
//    (2 issues) vs 3x ds_read_b64; -33% LDS issues in hot loop. Slab 37KB,
//    occupancy still thread-capped (4 blocks/CU x 37KB = 148KB < 160KB).
//  - phase2 out stores nontemporal (write-once stream; spare L2 for ws2).
//  Structure (proven R6-R8): pack ft->bf16 [p][pix][c], per-part LDS slab
//  gather with separable <=4x<=4 footprint, bf16-pair blocked ws, 64n-slab
//  transpose+unpack. Harness poison floor ~55-57us of dur.

constexpr int C  = 10;
constexpr int PH = 7;
constexpr int PW = 7;
constexpr int H  = 34;
constexpr int W  = 34;
constexpr int P  = PH * PW;         // 49
constexpr int HW = H * W;           // 1156
constexpr int FT_C_STRIDE = P * HW; // 56644
constexpr int SPX = 16;             // ushorts per pixel (10 ch + 6 pad), 32B
constexpr int SLAB_US = HW * SPX;   // 18496 ushorts = 36992 B
constexpr int CPAD = 12;            // fp32 fallback pad
constexpr int R  = C * P;           // 490
constexpr int RU = (C / 2) * P;     // 245 uint rows (bf16 channel pairs)

typedef float vf2 __attribute__((ext_vector_type(2)));  // native vec for NT store

__device__ inline unsigned bf16rn(float f) {
    unsigned u = __float_as_uint(f);
    return (u + 0x7FFFu + ((u >> 16) & 1u)) >> 16;
}
__device__ inline float bf16lo(unsigned u) { return __uint_as_float(u << 16); }
__device__ inline float bf16hi(unsigned u) { return __uint_as_float(u & 0xFFFF0000u); }

// ---- pack ft (C,P,H,W) fp32 -> ftB[p][pix][16 bf16]; grid (49,5) ----
__global__ __launch_bounds__(256) void dfmb_pack(
    const float* __restrict__ ft, ushort* __restrict__ ftB)
{
    const int p   = blockIdx.x;
    const int pix = blockIdx.y * 256 + threadIdx.x;
    if (pix >= HW) return;
    const float* __restrict__ src = ft + p * HW;
    unsigned d[8];
#pragma unroll
    for (int k = 0; k < 5; ++k) {
        float a = src[(2 * k) * FT_C_STRIDE + pix];
        float b = src[(2 * k + 1) * FT_C_STRIDE + pix];
        d[k] = bf16rn(a) | (bf16rn(b) << 16);
    }
    d[5] = 0; d[6] = 0; d[7] = 0;
    uint4* dst = (uint4*)(ftB + (size_t)p * SLAB_US + pix * SPX);
    dst[0] = make_uint4(d[0], d[1], d[2], d[3]);
    dst[1] = make_uint4(d[4], d[5], d[6], d[7]);
}

// ---- main: bf16 LDS slab gather, bf16-pair packed blocked ws out ----
__global__ __launch_bounds__(512) void dfmb_main(
    const ushort* __restrict__ ftB,
    const float* __restrict__ rois,
    unsigned* __restrict__ ws,  // [n/64][c2*49+p][n%64] bf16 pairs
    int N)
{
    __shared__ ushort slab[SLAB_US];    // 36992 B

    const int p  = blockIdx.y;
    const int ph = p / PW;
    const int pw = p - ph * PW;

    // Dense conflict-free staging: 2312 uint4 over 512 threads.
    {
        const uint4* __restrict__ s4 = (const uint4*)(ftB + (size_t)p * SLAB_US);
        uint4* d4 = (uint4*)slab;
        for (int i = threadIdx.x; i < SLAB_US / 8; i += 512) d4[i] = s4[i];
    }
    __syncthreads();

    const int n = blockIdx.x * 512 + threadIdx.x;
    if (n >= N) return;

    // Coordinate setup — contraction OFF so floor() args match the reference
    // rounding (verified passing R0-R8).
    float wstart, hstart, sub_w, sub_h;
    {
#pragma clang fp contract(off)
        const float inv_stride = 0.0625f;
        float rsw = rois[n * 5 + 1] * inv_stride;
        float rsh = rois[n * 5 + 2] * inv_stride;
        float rew = rois[n * 5 + 3] * inv_stride;
        float reh = rois[n * 5 + 4] * inv_stride;
        float roi_h = reh - rsh; if (!(roi_h > 0.1f)) roi_h = 0.1f;
        float roi_w = rew - rsw; if (!(roi_w > 0.1f)) roi_w = 0.1f;
        float bin_h = roi_h / 7.0f;
        float bin_w = roi_w / 7.0f;
        sub_h = bin_h * 0.25f;
        sub_w = bin_w * 0.25f;
        hstart = floorf(rsh + (float)ph * bin_h);
        wstart = floorf(rsw + (float)pw * bin_w);
    }

    // ---- separable 1-D weight footprints (<=4 cols x <=4 rows) ----
    float Xw0 = 0.f, Xw1 = 0.f, Xw2 = 0.f, Xw3 = 0.f, cntx = 0.f;
    int xbase = 0;
#pragma unroll
    for (int iw = 0; iw < 4; ++iw) {
        float w;
        {
#pragma clang fp contract(off)
            w = wstart + ((float)iw + 0.5f) * sub_w;
        }
        float kw  = (w > -1.0f && w < 34.0f) ? 1.0f : 0.0f;
        float x1f = floorf(w), x2f = ceilf(w);
        float x1v = (x1f >= 0.0f && x1f < 34.0f) ? 1.0f : 0.0f;
        float x2v = (x2f >= 0.0f && x2f < 34.0f) ? 1.0f : 0.0f;
        int x1 = (int)fminf(fmaxf(x1f, 0.0f), 33.0f);
        int x2 = (int)fminf(fmaxf(x2f, 0.0f), 33.0f);
        float dx = w - (float)x1;           // vs CLAMPED corner (ref semantics)
        if (iw == 0) xbase = x1;            // minimal column (w monotone in iw)
        float a = kw * (1.0f - dx) * x1v;
        float b = kw * dx * x2v;
        int i1 = x1 - xbase, i2 = x2 - xbase;
        Xw0 += (i1 == 0) ? a : 0.f;  Xw1 += (i1 == 1) ? a : 0.f;
        Xw2 += (i1 == 2) ? a : 0.f;  Xw3 += (i1 == 3) ? a : 0.f;
        Xw0 += (i2 == 0) ? b : 0.f;  Xw1 += (i2 == 1) ? b : 0.f;
        Xw2 += (i2 == 2) ? b : 0.f;  Xw3 += (i2 == 3) ? b : 0.f;
        cntx += kw;
    }

    float Yw0 = 0.f, Yw1 = 0.f, Yw2 = 0.f, Yw3 = 0.f, cnty = 0.f;
    int ybase = 0;
#pragma unroll
    for (int ih = 0; ih < 4; ++ih) {
        float h;
        {
#pragma clang fp contract(off)
            h = hstart + ((float)ih + 0.5f) * sub_h;
        }
        float kh  = (h > -1.0f && h < 34.0f) ? 1.0f : 0.0f;
        float y1f = floorf(h), y2f = ceilf(h);
        float y1v = (y1f >= 0.0f && y1f < 34.0f) ? 1.0f : 0.0f;
        float y2v = (y2f >= 0.0f && y2f < 34.0f) ? 1.0f : 0.0f;
        int y1 = (int)fminf(fmaxf(y1f, 0.0f), 33.0f);
        int y2 = (int)fminf(fmaxf(y2f, 0.0f), 33.0f);
        float dy = h - (float)y1;
        if (ih == 0) ybase = y1;
        float a = kh * (1.0f - dy) * y1v;
        float b = kh * dy * y2v;
        int i1 = y1 - ybase, i2 = y2 - ybase;
        Yw0 += (i1 == 0) ? a : 0.f;  Yw1 += (i1 == 1) ? a : 0.f;
        Yw2 += (i1 == 2) ? a : 0.f;  Yw3 += (i1 == 3) ? a : 0.f;
        Yw0 += (i2 == 0) ? b : 0.f;  Yw1 += (i2 == 1) ? b : 0.f;
        Yw2 += (i2 == 2) ? b : 0.f;  Yw3 += (i2 == 3) ? b : 0.f;
        cnty += kh;
    }

    // ---- accumulate over footprint: b128 + b64 per pixel (10 bf16 ch) ----
    float s0=0.f,s1=0.f,s2=0.f,s3=0.f,s4=0.f,s5=0.f,s6=0.f,s7=0.f,s8=0.f,s9=0.f;
#pragma unroll
    for (int cy = 0; cy < 4; ++cy) {
        float wy = (cy == 0) ? Yw0 : (cy == 1) ? Yw1 : (cy == 2) ? Yw2 : Yw3;
        if (wy != 0.0f) {
            int yy = min(ybase + cy, 33);
            const ushort* rowp = slab + yy * (W * SPX);
#pragma unroll
            for (int cx = 0; cx < 4; ++cx) {
                float wx = (cx == 0) ? Xw0 : (cx == 1) ? Xw1
                         : (cx == 2) ? Xw2 : Xw3;
                float wgt = wy * wx;
                if (wgt != 0.0f) {
                    int xx = min(xbase + cx, 33);
                    const ushort* t = rowp + xx * SPX;
                    uint4 a = *(const uint4*)(t);       // ch 0..7
                    uint2 b = *(const uint2*)(t + 8);   // ch 8..9 (+pad)
                    s0 += wgt * bf16lo(a.x);  s1 += wgt * bf16hi(a.x);
                    s2 += wgt * bf16lo(a.y);  s3 += wgt * bf16hi(a.y);
                    s4 += wgt * bf16lo(a.z);  s5 += wgt * bf16hi(a.z);
                    s6 += wgt * bf16lo(a.w);  s7 += wgt * bf16hi(a.w);
                    s8 += wgt * bf16lo(b.x);  s9 += wgt * bf16hi(b.x);
                }
            }
        }
    }

    float cnt = cntx * cnty;
    if (!(cnt > 0.0f)) cnt = 1.0f;
    float inv = 1.0f / cnt;

    // Pack 10 results into 5 bf16-pair uints; blocked coalesced stores.
    unsigned r01 = bf16rn(s0 * inv) | (bf16rn(s1 * inv) << 16);
    unsigned r23 = bf16rn(s2 * inv) | (bf16rn(s3 * inv) << 16);
    unsigned r45 = bf16rn(s4 * inv) | (bf16rn(s5 * inv) << 16);
    unsigned r67 = bf16rn(s6 * inv) | (bf16rn(s7 * inv) << 16);
    unsigned r89 = bf16rn(s8 * inv) | (bf16rn(s9 * inv) << 16);

    unsigned* __restrict__ o = ws + (size_t)(n >> 6) * (RU * 64)
                                  + (size_t)p * 64 + (n & 63);
    o[0 * (P * 64)] = r01;
    o[1 * (P * 64)] = r23;
    o[2 * (P * 64)] = r45;
    o[3 * (P * 64)] = r67;
    o[4 * (P * 64)] = r89;
}

// Per-64n-slab transpose+unpack: ws[nblk][c2*49+p][nl] (245x64 uints,
// contiguous 62.7KB) -> out[n][c*49+p] fp32, nontemporal vf2 stores.
__global__ __launch_bounds__(1024) void dfmb_phase2(
    const unsigned* __restrict__ ws, float* __restrict__ out, int N)
{
    __shared__ unsigned t[RU * 65];     // 63700 B
    const int nblk = blockIdx.x;
    const unsigned* __restrict__ srcb = ws + (size_t)nblk * (RU * 64);

    // Load 245 rows x 64 nl contiguous via uint4 (3920 of them).
    for (int i = threadIdx.x; i < RU * 16; i += 1024) {
        int rr  = i >> 4;
        int nl4 = (i & 15) * 4;
        uint4 v = ((const uint4*)srcb)[i];
        unsigned* tp = &t[rr * 65 + nl4];
        tp[0] = v.x; tp[1] = v.y; tp[2] = v.z; tp[3] = v.w;
    }
    __syncthreads();

    // Write out[n0+nl][2k..2k+1]: lane-consecutive k -> coalesced 512B vf2.
    const int n0 = nblk * 64;
    for (int j = threadIdx.x; j < 64 * (R / 2); j += 1024) {
        int nl = j / (R / 2);
        int k  = j - nl * (R / 2);
        int r0 = 2 * k, r1 = 2 * k + 1;
        int c0 = r0 / P, p0 = r0 - c0 * P;
        int c1 = r1 / P, p1 = r1 - c1 * P;
        unsigned u0 = t[((c0 >> 1) * P + p0) * 65 + nl];
        unsigned u1 = t[((c1 >> 1) * P + p1) * 65 + nl];
        vf2 v;
        v.x = (c0 & 1) ? bf16hi(u0) : bf16lo(u0);
        v.y = (c1 & 1) ? bf16hi(u1) : bf16lo(u1);
        __builtin_nontemporal_store(v, (vf2*)(out + (size_t)(n0 + nl) * R) + k);
    }
}

// ---- fallback (no ws): fp32 LDS-slab kernel, direct strided writes ----
__global__ __launch_bounds__(512, 4) void dfmb_phase1_direct(
    const float* __restrict__ ft,
    const float* __restrict__ rois,
    float* __restrict__ dst,
    int N)
{
    __shared__ float tile[HW * CPAD];
    const int p  = blockIdx.y;
    const int ph = p / PW;
    const int pw = p - ph * PW;
    const float* __restrict__ src = ft + p * HW;
    for (int i = threadIdx.x; i < C * HW; i += 512) {
        int c = i / HW;
        int r = i - c * HW;
        tile[r * CPAD + c] = src[c * FT_C_STRIDE + r];
    }
    __syncthreads();
    const int n = blockIdx.x * 512 + threadIdx.x;
    if (n >= N) return;
    float wstart, hstart, sub_w, sub_h;
    {
#pragma clang fp contract(off)
        const float inv_stride = 0.0625f;
        float rsw = rois[n * 5 + 1] * inv_stride;
        float rsh = rois[n * 5 + 2] * inv_stride;
        float rew = rois[n * 5 + 3] * inv_stride;
        float reh = rois[n * 5 + 4] * inv_stride;
        float roi_h = reh - rsh; if (!(roi_h > 0.1f)) roi_h = 0.1f;
        float roi_w = rew - rsw; if (!(roi_w > 0.1f)) roi_w = 0.1f;
        float bin_h = roi_h / 7.0f;
        float bin_w = roi_w / 7.0f;
        sub_h = bin_h * 0.25f;
        sub_w = bin_w * 0.25f;
        hstart = floorf(rsh + (float)ph * bin_h);
        wstart = floorf(rsw + (float)pw * bin_w);
    }
    float Xw0=0.f,Xw1=0.f,Xw2=0.f,Xw3=0.f,cntx=0.f;
    float Yw0=0.f,Yw1=0.f,Yw2=0.f,Yw3=0.f,cnty=0.f;
    int xbase = 0, ybase = 0;
#pragma unroll
    for (int iw = 0; iw < 4; ++iw) {
        float w;
        {
#pragma clang fp contract(off)
            w = wstart + ((float)iw + 0.5f) * sub_w;
        }
        float kw  = (w > -1.0f && w < 34.0f) ? 1.0f : 0.0f;
        float x1f = floorf(w), x2f = ceilf(w);
        float x1v = (x1f >= 0.0f && x1f < 34.0f) ? 1.0f : 0.0f;
        float x2v = (x2f >= 0.0f && x2f < 34.0f) ? 1.0f : 0.0f;
        int x1 = (int)fminf(fmaxf(x1f, 0.0f), 33.0f);
        int x2 = (int)fminf(fmaxf(x2f, 0.0f), 33.0f);
        float dx = w - (float)x1;
        if (iw == 0) xbase = x1;
        float a = kw * (1.0f - dx) * x1v;
        float b = kw * dx * x2v;
        int i1 = x1 - xbase, i2 = x2 - xbase;
        Xw0 += (i1==0)?a:0.f; Xw1 += (i1==1)?a:0.f; Xw2 += (i1==2)?a:0.f; Xw3 += (i1==3)?a:0.f;
        Xw0 += (i2==0)?b:0.f; Xw1 += (i2==1)?b:0.f; Xw2 += (i2==2)?b:0.f; Xw3 += (i2==3)?b:0.f;
        cntx += kw;
    }
#pragma unroll
    for (int ih = 0; ih < 4; ++ih) {
        float h;
        {
#pragma clang fp contract(off)
            h = hstart + ((float)ih + 0.5f) * sub_h;
        }
        float kh  = (h > -1.0f && h < 34.0f) ? 1.0f : 0.0f;
        float y1f = floorf(h), y2f = ceilf(h);
        float y1v = (y1f >= 0.0f && y1f < 34.0f) ? 1.0f : 0.0f;
        float y2v = (y2f >= 0.0f && y2f < 34.0f) ? 1.0f : 0.0f;
        int y1 = (int)fminf(fmaxf(y1f, 0.0f), 33.0f);
        int y2 = (int)fminf(fmaxf(y2f, 0.0f), 33.0f);
        float dy = h - (float)y1;
        if (ih == 0) ybase = y1;
        float a = kh * (1.0f - dy) * y1v;
        float b = kh * dy * y2v;
        int i1 = y1 - ybase, i2 = y2 - ybase;
        Yw0 += (i1==0)?a:0.f; Yw1 += (i1==1)?a:0.f; Yw2 += (i1==2)?a:0.f; Yw3 += (i1==3)?a:0.f;
        Yw0 += (i2==0)?b:0.f; Yw1 += (i2==1)?b:0.f; Yw2 += (i2==2)?b:0.f; Yw3 += (i2==3)?b:0.f;
        cnty += kh;
    }
    float4 v0s = {0,0,0,0}, v1s = {0,0,0,0};
    float2 v2s = {0,0};
#pragma unroll
    for (int cy = 0; cy < 4; ++cy) {
        float wy = (cy==0)?Yw0:(cy==1)?Yw1:(cy==2)?Yw2:Yw3;
        if (wy != 0.0f) {
            int yy = min(ybase + cy, 33);
            const float* rowp = &tile[yy * (W * CPAD)];
#pragma unroll
            for (int cx = 0; cx < 4; ++cx) {
                float wx = (cx==0)?Xw0:(cx==1)?Xw1:(cx==2)?Xw2:Xw3;
                float wgt = wy * wx;
                if (wgt != 0.0f) {
                    int xx = min(xbase + cx, 33);
                    const float* t = rowp + xx * CPAD;
                    float4 a = *(const float4*)(t);
                    float4 b = *(const float4*)(t + 4);
                    float2 c2 = *(const float2*)(t + 8);
                    v0s.x += wgt*a.x; v0s.y += wgt*a.y; v0s.z += wgt*a.z; v0s.w += wgt*a.w;
                    v1s.x += wgt*b.x; v1s.y += wgt*b.y; v1s.z += wgt*b.z; v1s.w += wgt*b.w;
                    v2s.x += wgt*c2.x; v2s.y += wgt*c2.y;
                }
            }
        }
    }
    float cnt = cntx * cnty;
    if (!(cnt > 0.0f)) cnt = 1.0f;
    float inv = 1.0f / cnt;
    float r[10] = { v0s.x*inv, v0s.y*inv, v0s.z*inv, v0s.w*inv,
                    v1s.x*inv, v1s.y*inv, v1s.z*inv, v1s.w*inv,
                    v2s.x*inv, v2s.y*inv };
    float* __restrict__ o = dst + (size_t)n * R + p;
#pragma unroll
    for (int c = 0; c < C; ++c) o[c * P] = r[c];
}

extern "C" void kernel_launch(void* const* d_in, const int* in_sizes, int n_in,
                              void* d_out, int out_size, void* d_ws, size_t ws_size,
                              hipStream_t stream) {
    const float* ft   = (const float*)d_in[0];
    const float* rois = (const float*)d_in[1];
    float* out = (float*)d_out;
    const int N = in_sizes[1] / 5;

    const size_t packB = (size_t)P * SLAB_US * sizeof(ushort); // 1.81 MB
    const size_t wsOff = (packB + 255) & ~(size_t)255;
    const size_t need  = wsOff + (size_t)RU * N * sizeof(unsigned); // +16 MB
    if (d_ws != nullptr && ws_size >= need && (N % 64) == 0) {
        ushort*   ftB = (ushort*)d_ws;
        unsigned* ws2 = (unsigned*)((char*)d_ws + wsOff);
        dfmb_pack<<<dim3(P, (HW + 255) / 256), dim3(256), 0, stream>>>(ft, ftB);
        dfmb_main<<<dim3((N + 511) / 512, P), dim3(512), 0, stream>>>(ftB, rois, ws2, N);
        dfmb_phase2<<<dim3(N / 64), dim3(1024), 0, stream>>>(ws2, out, N);
    } else {
        dim3 grid1((N + 511) / 512, P);
        dfmb_phase1_direct<<<grid1, dim3(512), 0, stream>>>(ft, rois, out, N);
    }
}